// Round 6
// baseline (1158.463 us; speedup 1.0000x reference)
//
#include <hip/hip_runtime.h>
#include <hip/hip_bf16.h>
#include <stdint.h>

#define B_   64
#define C_   3
#define J_   25
#define T_   256
#define CO_  64
#define N_   (B_*J_*T_)     // 409600 locations, loc = (b*J_+j)*T_ + t
#define SIGD 84
#define FSTR 177            // feats LDS stride (f32) — (17*lt+k)%32: 2-way banks only
#define WST  136            // w12 bf16 row stride (elements), K=128 + 8 pad

typedef short   s16x8  __attribute__((ext_vector_type(8)));
typedef __bf16  bf16x8 __attribute__((ext_vector_type(8)));
typedef float   f32x4  __attribute__((ext_vector_type(4)));
typedef float   f32x2  __attribute__((ext_vector_type(2)));

__device__ __forceinline__ unsigned short f2b(float f) {
    unsigned int u = __float_as_uint(f);
    u += 0x7fffu + ((u >> 16) & 1u);          // round-to-nearest-even
    return (unsigned short)(u >> 16);
}
__device__ __forceinline__ float b2f(unsigned int bits_lo16) {
    return __uint_as_float(bits_lo16 << 16);
}
__device__ __forceinline__ unsigned int pack2(float a, float b) {
    return (unsigned int)f2b(a) | ((unsigned int)f2b(b) << 16);
}
__device__ __forceinline__ void split2(float f, unsigned short& h, unsigned short& l) {
    h = f2b(f);
    l = f2b(f - b2f((unsigned int)h));
}

// ---------------------------------------------------------------------------
// depth-3 signature of a 3-increment path in 4 dims (verified).
// ---------------------------------------------------------------------------
__device__ __forceinline__ void sig3(const float v0[4], const float v1[4],
                                     const float v2[4], float* __restrict__ S) {
    float* S1 = S;
    float* S2 = S + 4;
    float* S3 = S + 20;
    #pragma unroll
    for (int i = 0; i < 4; i++) S1[i] = v0[i];
    #pragma unroll
    for (int i = 0; i < 4; i++)
        #pragma unroll
        for (int j = 0; j < 4; j++) S2[i*4+j] = 0.5f * v0[i] * v0[j];
    #pragma unroll
    for (int i = 0; i < 4; i++)
        #pragma unroll
        for (int j = 0; j < 4; j++)
            #pragma unroll
            for (int k = 0; k < 4; k++)
                S3[i*16+j*4+k] = S2[i*4+j] * v0[k] * (1.f/3.f);

    #pragma unroll
    for (int s = 0; s < 2; s++) {
        const float* v = (s == 0) ? v1 : v2;
        float B2[16], v3[4];
        #pragma unroll
        for (int k = 0; k < 4; k++) v3[k] = v[k] * (1.f/3.f);
        #pragma unroll
        for (int i = 0; i < 4; i++)
            #pragma unroll
            for (int j = 0; j < 4; j++) B2[i*4+j] = 0.5f * v[i] * v[j];
        #pragma unroll
        for (int i = 0; i < 4; i++)
            #pragma unroll
            for (int j = 0; j < 4; j++)
                #pragma unroll
                for (int k = 0; k < 4; k++)
                    S3[i*16+j*4+k] += B2[i*4+j]*v3[k] + S1[i]*B2[j*4+k] + S2[i*4+j]*v[k];
        #pragma unroll
        for (int i = 0; i < 4; i++)
            #pragma unroll
            for (int j = 0; j < 4; j++) S2[i*4+j] += B2[i*4+j] + S1[i]*v[j];
        #pragma unroll
        for (int i = 0; i < 4; i++) S1[i] += v[i];
    }
}

// ---------------------------------------------------------------------------
// K0: fold signet weights through ps_w into f32 wsig_t[168][64] (k-major).
// grid=169 (k; 168=bias), block=64 (o).   (verified baseline)
// ---------------------------------------------------------------------------
__global__ void k_prep(const float* __restrict__ sp_W, const float* __restrict__ sp_b,
                       const float* __restrict__ tp_W, const float* __restrict__ tp_b,
                       const float* __restrict__ ps_w, const float* __restrict__ ps_b,
                       float* __restrict__ wsig_t, float* __restrict__ cb) {
    int k = blockIdx.x;
    int o = threadIdx.x;
    if (k < SIGD) {
        float v = 0.f;
        for (int i = 0; i < 64; i++) v += sp_W[k*64+i] * ps_w[o*128+i];
        wsig_t[k*64 + o] = v;
    } else if (k < 2*SIGD) {
        int m = k - SIGD;
        float v = 0.f;
        for (int i = 0; i < 64; i++) v += tp_W[m*64+i] * ps_w[o*128+64+i];
        wsig_t[k*64 + o] = v;
    } else {
        float a = ps_b[o];
        for (int i = 0; i < 64; i++)
            a += ps_w[o*128+i]*sp_b[i] + ps_w[o*128+64+i]*tp_b[i];
        cb[o] = a;
    }
}

// ---------------------------------------------------------------------------
// K1: fused conv1x3 + signatures + packed-f32 folded matvec (VERIFIED
// baseline phases A and B) + NEW appended stats post-pass: per-block
// sum/ssq over its own 64 zcat rows (L2-hot re-read), xor-shuffle wave
// reduce, 8-slotted atomicAdd.  Replaces the separate k_stats<128> kernel.
// Grid: 1600 (b,j) x 4 quarters, 64 locs/block.
// ---------------------------------------------------------------------------
__global__ __launch_bounds__(256) void k_sig(const float* __restrict__ x,
                                             const int* __restrict__ nbr,
                                             const float* __restrict__ wsig_t,
                                             const float* __restrict__ cb,
                                             const float* __restrict__ conv_w,
                                             const float* __restrict__ conv_b,
                                             unsigned short* __restrict__ zcat,
                                             float* __restrict__ sum_cp8,
                                             float* __restrict__ ssq_cp8) {
    __shared__ float feats[64*FSTR];   // 45312 B

    const int i       = threadIdx.x;
    const int quarter = blockIdx.x & 3;
    const int bj      = blockIdx.x >> 2;
    const int b       = bj / J_, j = bj % J_;
    const int loc_base = bj*T_ + quarter*64;

    if (i < 128) {
        const int lt   = i >> 1;
        const int path = i & 1;
        const int t    = quarter*64 + lt;
        float p0[4], p1[4], p2[4];
        p0[0] = 0.f; p1[0] = 0.5f; p2[0] = 1.0f;
        if (path == 0) {
            int n0 = nbr[j*3+0], n1 = nbr[j*3+1], n2 = nbr[j*3+2];
            #pragma unroll
            for (int c = 0; c < 3; c++) {
                const float* xc = x + ((size_t)(b*3+c)*J_)*T_ + t;
                p0[c+1] = xc[n0*T_];
                p1[c+1] = xc[n1*T_];
                p2[c+1] = xc[n2*T_];
            }
        } else {
            int tm = (t > 0)    ? t-1 : 0;
            int tp = (t < T_-1) ? t+1 : T_-1;
            #pragma unroll
            for (int c = 0; c < 3; c++) {
                const float* xr = x + ((size_t)(b*3+c)*J_ + j)*T_;
                p0[c+1] = xr[tm];
                p1[c+1] = xr[t];
                p2[c+1] = xr[tp];
            }
        }
        float v0[4], v1[4], v2[4];
        #pragma unroll
        for (int d = 0; d < 4; d++) { v0[d]=p0[d]; v1[d]=p1[d]-p0[d]; v2[d]=p2[d]-p1[d]; }
        float S[SIGD];
        sig3(v0, v1, v2, S);
        float* frow = feats + lt*FSTR + path*SIGD;
        #pragma unroll
        for (int m = 0; m < SIGD; m++) frow[m] = S[m];
    } else {
        const int ci  = i - 128;
        const int lt  = ci >> 1;
        const int chh = ci & 1;
        const int t   = quarter*64 + lt;
        const int loc = loc_base + lt;
        float xm[3], x0[3], xp[3];
        #pragma unroll
        for (int c = 0; c < 3; c++) {
            const float* xr = x + ((size_t)(b*3+c)*J_ + j)*T_;
            xm[c] = (t > 0)     ? xr[t-1] : 0.f;
            x0[c] = xr[t];
            xp[c] = (t < T_-1)  ? xr[t+1] : 0.f;
        }
        unsigned int packed[16];
        #pragma unroll
        for (int oo2 = 0; oo2 < 16; oo2++) {
            float r[2];
            #pragma unroll
            for (int e = 0; e < 2; e++) {
                int o = chh*32 + oo2*2 + e;
                float acc = conv_b[o];
                #pragma unroll
                for (int c = 0; c < 3; c++) {
                    const float* wr = conv_w + (o*3+c)*3;
                    acc += wr[0]*xm[c] + wr[1]*x0[c] + wr[2]*xp[c];
                }
                r[e] = fmaxf(acc, 0.f);
            }
            packed[oo2] = pack2(r[0], r[1]);
        }
        uint4* dst = (uint4*)(zcat + (size_t)loc*128 + chh*32);
        #pragma unroll
        for (int k = 0; k < 4; k++)
            dst[k] = make_uint4(packed[k*4+0], packed[k*4+1], packed[k*4+2], packed[k*4+3]);
    }
    __syncthreads();

    // ---- packed matvec: z_ps[loc][o] = relu(sum_k w[k][o]*f[loc][k]+cb) ----
    {
        const int og = __builtin_amdgcn_readfirstlane(i >> 6);   // wave-uniform o-tile
        const int lt = i & 63;
        const int loc = loc_base + lt;
        const float* wt = wsig_t + og*16;        // + k*64
        f32x2 acc2[8];
        {
            const f32x2* cbp = (const f32x2*)(cb + og*16);
            #pragma unroll
            for (int p = 0; p < 8; p++) acc2[p] = cbp[p];
        }
        const float* frow = feats + lt*FSTR;
        #pragma unroll 4
        for (int k = 0; k < 2*SIGD; k++) {
            float f = frow[k];
            f32x2 f2 = { f, f };
            const f32x2* w2 = (const f32x2*)(wt + k*64);
            #pragma unroll
            for (int p = 0; p < 8; p++) acc2[p] += f2 * w2[p];   // v_pk_fma_f32
        }
        unsigned int pk[8];
        #pragma unroll
        for (int p = 0; p < 8; p++)
            pk[p] = pack2(fmaxf(acc2[p][0],0.f), fmaxf(acc2[p][1],0.f));
        uint4* dst = (uint4*)(zcat + (size_t)loc*128 + 64 + og*16);
        dst[0] = make_uint4(pk[0], pk[1], pk[2], pk[3]);
        dst[1] = make_uint4(pk[4], pk[5], pk[6], pk[7]);
    }

    // ---- NEW: fused stats post-pass over this block's 64 zcat rows ----
    // __syncthreads drains vmcnt before s_barrier => all zcat stores of this
    // block are at L2; the lines were never read before in this kernel, so
    // loads miss L1 and hit the fresh L2 data.
    __syncthreads();
    {
        const int g2  = i & 15;          // 16 channel-groups of 8 (ch = g2*8+k)
        const int lr2 = i >> 4;          // 16 row-groups of 4 rows
        float s[8], q[8];
        #pragma unroll
        for (int k = 0; k < 8; k++) { s[k] = 0.f; q[k] = 0.f; }
        #pragma unroll
        for (int li = 0; li < 4; li++) {
            const int l = lr2 + li*16;
            const uint4 v = *(const uint4*)(zcat + (size_t)(loc_base + l)*128 + g2*8);
            unsigned int u[4] = { v.x, v.y, v.z, v.w };
            #pragma unroll
            for (int k = 0; k < 4; k++) {
                float f0 = b2f(u[k] & 0xffffu);
                float f1 = __uint_as_float(u[k] & 0xffff0000u);
                s[2*k]   += f0;  q[2*k]   += f0*f0;
                s[2*k+1] += f1;  q[2*k+1] += f1*f1;
            }
        }
        // reduce across the 4 lanes sharing (lane&15) in this wave: xor 16,32
        #pragma unroll
        for (int off = 16; off <= 32; off <<= 1) {
            #pragma unroll
            for (int k = 0; k < 8; k++) {
                s[k] += __shfl_xor(s[k], off);
                q[k] += __shfl_xor(q[k], off);
            }
        }
        const int lane = i & 63;
        if (lane < 16) {                 // one lane per channel-group per wave
            const int slot = blockIdx.x & 7;
            float* sb = sum_cp8 + slot*128 + g2*8;
            float* qb = ssq_cp8 + slot*128 + g2*8;
            #pragma unroll
            for (int k = 0; k < 8; k++) {
                atomicAdd(sb + k, s[k]);
                atomicAdd(qb + k, q[k]);
            }
        }
    }
}

// ---------------------------------------------------------------------------
// K3: finalize conv/ps BN (8-slot sums); fold into fu weights.
// ---------------------------------------------------------------------------
__global__ void k_fin1(const float* __restrict__ sum_cp8, const float* __restrict__ ssq_cp8,
                       const float* __restrict__ raw_g, const float* __restrict__ raw_b,
                       const float* __restrict__ ps_g,  const float* __restrict__ ps_bt,
                       const float* __restrict__ fu_w,  const float* __restrict__ fu_b,
                       unsigned short* __restrict__ w12h, unsigned short* __restrict__ w12l,
                       float* __restrict__ w12s_t, float* __restrict__ fb2) {
    __shared__ float a[128], d[128];
    int i = threadIdx.x;    // 64
    const float inv = 1.f / (float)N_;
    float s0 = 0.f, q0 = 0.f, s1 = 0.f, q1 = 0.f;
    for (int sl = 0; sl < 8; sl++) {
        s0 += sum_cp8[sl*128 + i];       q0 += ssq_cp8[sl*128 + i];
        s1 += sum_cp8[sl*128 + 64 + i];  q1 += ssq_cp8[sl*128 + 64 + i];
    }
    {
        float m = s0*inv, v = q0*inv - m*m;
        float sc = rsqrtf(v + 1e-5f) * raw_g[i];
        a[i] = sc; d[i] = raw_b[i] - m*sc;
    }
    {
        float m = s1*inv, v = q1*inv - m*m;
        float sc = rsqrtf(v + 1e-5f) * ps_g[i];
        a[64+i] = sc; d[64+i] = ps_bt[i] - m*sc;
    }
    __syncthreads();
    int o = i;
    float fb = fu_b[o];
    for (int k = 0; k < 128; k++) {
        float w = fu_w[o*128 + k];
        fb += w * d[k];
        float ws = w * a[k];
        w12s_t[k*64 + o] = ws;
        unsigned short h, l;
        split2(ws, h, l);
        w12h[o*WST + k] = h;
        w12l[o*WST + k] = l;
    }
    for (int k = 128; k < WST; k++) { w12h[o*WST + k] = 0; w12l[o*WST + k] = 0; }
    fb2[o] = fb;
}

// ---------------------------------------------------------------------------
// K4: fu GEMM via MFMA with in-kernel C/D-orientation probe (verified
// baseline) + NEW appended stats post-pass over this block's 128 z_fu rows
// (path-independent: reads z_fu regardless of which branch wrote it).
// Replaces the separate k_stats<64> kernel.
// ---------------------------------------------------------------------------
__global__ __launch_bounds__(256) void k_fu(const unsigned short* __restrict__ zcat,
                                            const unsigned short* __restrict__ w12h,
                                            const unsigned short* __restrict__ w12l,
                                            const float* __restrict__ w12s_t,
                                            const float* __restrict__ fb2,
                                            unsigned short* __restrict__ z_fu,
                                            float* __restrict__ sum_f8,
                                            float* __restrict__ ssq_f8) {
    __shared__ __align__(16) unsigned short zt[128*WST];   // 34816 B
    const int i = threadIdx.x;
    const int loc_base = blockIdx.x * 128;

    for (int c = i; c < 2048; c += 256) {
        int row = c >> 4, k = c & 15;
        s16x8 v = *(const s16x8*)(zcat + (size_t)(loc_base + row)*128 + k*8);
        *(s16x8*)(zt + row*WST + k*8) = v;
    }
    __syncthreads();

    const int lane = i & 63, wv = i >> 6;
    const int mrow = lane & 15, q = lane >> 4;
    const f32x4 zero = {0.f, 0.f, 0.f, 0.f};

    // ---- layout probe ----
    bf16x8 ap, bp;
    #pragma unroll
    for (int jj = 0; jj < 8; jj++) { ap[jj] = (__bf16)(float)mrow; bp[jj] = (__bf16)1.0f; }
    f32x4 pv = __builtin_amdgcn_mfma_f32_16x16x32_bf16(ap, bp, zero, 0, 0, 0);
    bool cC = true, cT = true;
    #pragma unroll
    for (int r = 0; r < 4; r++) {
        cC = cC && (pv[r] == 32.f*(float)(q*4 + r));
        cT = cT && (pv[r] == 32.f*(float)mrow);
    }
    const bool okC = (__ballot(cC) == ~0ull);
    const bool okT = (!okC) && (__ballot(cT) == ~0ull);

    if (okC || okT) {
        bf16x8 ah[4], al[4];
        {
            const unsigned short* arh = w12h + (size_t)(wv*16 + mrow)*WST + q*8;
            const unsigned short* arl = w12l + (size_t)(wv*16 + mrow)*WST + q*8;
            #pragma unroll
            for (int s = 0; s < 4; s++) {
                ah[s] = __builtin_bit_cast(bf16x8, *(const s16x8*)(arh + s*32));
                al[s] = __builtin_bit_cast(bf16x8, *(const s16x8*)(arl + s*32));
            }
        }
        f32x4 accs[8];
        #pragma unroll
        for (int lt8 = 0; lt8 < 8; lt8++) {
            const unsigned short* brow = zt + (size_t)(lt8*16 + mrow)*WST + q*8;
            f32x4 acc = zero;
            #pragma unroll
            for (int s = 0; s < 4; s++) {
                bf16x8 bfrag = __builtin_bit_cast(bf16x8, *(const s16x8*)(brow + s*32));
                acc = __builtin_amdgcn_mfma_f32_16x16x32_bf16(ah[s], bfrag, acc, 0, 0, 0);
                acc = __builtin_amdgcn_mfma_f32_16x16x32_bf16(al[s], bfrag, acc, 0, 0, 0);
            }
            accs[lt8] = acc;
        }
        __syncthreads();

        unsigned short* ot = zt;       // alias as [128 loc][72 o]
        if (okC) {
            const float4 fbv = *(const float4*)(fb2 + wv*16 + q*4);
            #pragma unroll
            for (int lt8 = 0; lt8 < 8; lt8++) {
                int row = lt8*16 + mrow;
                int o   = wv*16 + q*4;
                uint2 w;
                w.x = pack2(fmaxf(accs[lt8][0]+fbv.x,0.f), fmaxf(accs[lt8][1]+fbv.y,0.f));
                w.y = pack2(fmaxf(accs[lt8][2]+fbv.z,0.f), fmaxf(accs[lt8][3]+fbv.w,0.f));
                *(uint2*)(ot + row*72 + o) = w;
            }
        } else {
            const float fb1 = fb2[wv*16 + mrow];
            #pragma unroll
            for (int lt8 = 0; lt8 < 8; lt8++) {
                #pragma unroll
                for (int r = 0; r < 4; r++) {
                    int row = lt8*16 + q*4 + r;
                    ot[row*72 + wv*16 + mrow] = f2b(fmaxf(accs[lt8][r]+fb1, 0.f));
                }
            }
        }
        __syncthreads();
        for (int c = i; c < 1024; c += 256) {
            int row = c >> 3, k = c & 7;
            s16x8 v = *(const s16x8*)(ot + row*72 + k*8);
            *(s16x8*)(z_fu + (size_t)(loc_base + row)*64 + k*8) = v;
        }
    } else {
        // ---- scalar fallback (correctness net; slow but exact) ----
        if (i < 128) {
            const unsigned short* fr = zt + i*WST;
            const int loc = loc_base + i;
            for (int og8 = 0; og8 < 8; og8++) {
                float acc[8];
                #pragma unroll
                for (int p = 0; p < 8; p++) acc[p] = fb2[og8*8 + p];
                for (int k = 0; k < 128; k++) {
                    float f = b2f(fr[k]);
                    const float* w = w12s_t + k*64 + og8*8;
                    #pragma unroll
                    for (int p = 0; p < 8; p++) acc[p] = fmaf(f, w[p], acc[p]);
                }
                #pragma unroll
                for (int p = 0; p < 8; p++)
                    z_fu[(size_t)loc*64 + og8*8 + p] = f2b(fmaxf(acc[p], 0.f));
            }
        }
    }

    // ---- NEW: fused stats post-pass over this block's 128 z_fu rows ----
    __syncthreads();        // drains the z_fu stores of whichever path ran
    {
        const int g3  = i & 7;           // 8 channel-groups of 8 (ch = g3*8+k)
        const int lr3 = i >> 3;          // 32 row-groups of 4 rows
        float s[8], q2[8];
        #pragma unroll
        for (int k = 0; k < 8; k++) { s[k] = 0.f; q2[k] = 0.f; }
        #pragma unroll
        for (int li = 0; li < 4; li++) {
            const int l = lr3 + li*32;
            const uint4 v = *(const uint4*)(z_fu + (size_t)(loc_base + l)*64 + g3*8);
            unsigned int u[4] = { v.x, v.y, v.z, v.w };
            #pragma unroll
            for (int k = 0; k < 4; k++) {
                float f0 = b2f(u[k] & 0xffffu);
                float f1 = __uint_as_float(u[k] & 0xffff0000u);
                s[2*k]   += f0;  q2[2*k]   += f0*f0;
                s[2*k+1] += f1;  q2[2*k+1] += f1*f1;
            }
        }
        // reduce across the 8 lanes sharing (lane&7) in this wave: xor 8,16,32
        #pragma unroll
        for (int off = 8; off <= 32; off <<= 1) {
            #pragma unroll
            for (int k = 0; k < 8; k++) {
                s[k]  += __shfl_xor(s[k],  off);
                q2[k] += __shfl_xor(q2[k], off);
            }
        }
        if (lane < 8) {                  // one lane per channel-group per wave
            const int slot = blockIdx.x & 7;
            float* sb = sum_f8 + slot*64 + g3*8;
            float* qb = ssq_f8 + slot*64 + g3*8;
            #pragma unroll
            for (int k = 0; k < 8; k++) {
                atomicAdd(sb + k, s[k]);
                atomicAdd(qb + k, q2[k]);
            }
        }
    }
}

// ---------------------------------------------------------------------------
// K5: finalize fu BN stats (8-slot sums)
// ---------------------------------------------------------------------------
__global__ void k_fin2(const float* __restrict__ sum_f8, const float* __restrict__ ssq_f8,
                       const float* __restrict__ fu_g,
                       float* __restrict__ mf, float* __restrict__ rfg) {
    int o = threadIdx.x;
    const float inv = 1.f / (float)N_;
    float sm = 0.f, sq = 0.f;
    for (int sl = 0; sl < 8; sl++) { sm += sum_f8[sl*64 + o]; sq += ssq_f8[sl*64 + o]; }
    float m = sm*inv, v = sq*inv - m*m;
    mf[o] = m;
    rfg[o] = rsqrtf(v + 1e-5f) * fu_g[o];
}

// ---------------------------------------------------------------------------
// K6: apply fu BN, transpose [loc][64] -> out [b][o][j][t] f32. (unchanged)
// ---------------------------------------------------------------------------
__global__ __launch_bounds__(256) void k_out(const unsigned short* __restrict__ z_fu,
                                             const float* __restrict__ mf,
                                             const float* __restrict__ rfg,
                                             const float* __restrict__ fu_beta,
                                             float* __restrict__ out) {
    __shared__ __align__(16) unsigned short zt[256*66];
    const int i = threadIdx.x;
    const int bj = blockIdx.x;
    const int b = bj / J_, j = bj % J_;
    const int loc_base = bj * T_;

    for (int c = i; c < 2048; c += 256) {
        int row = c >> 3, k = c & 7;
        uint4 v = *(const uint4*)(z_fu + (size_t)(loc_base + row)*64 + k*8);
        unsigned int* dst = (unsigned int*)(zt + row*66 + k*8);
        dst[0] = v.x; dst[1] = v.y; dst[2] = v.z; dst[3] = v.w;
    }
    __syncthreads();

    const int t = i;
    const unsigned int* zrow = (const unsigned int*)zt + t*33;
    for (int o = 0; o < 64; o += 2) {
        unsigned int v = zrow[o >> 1];
        float f0 = b2f(v & 0xffffu);
        float f1 = __uint_as_float(v & 0xffff0000u);
        out[(((size_t)b*64 + o  )*J_ + j)*T_ + t] = (f0 - mf[o  ])*rfg[o  ] + fu_beta[o  ];
        out[(((size_t)b*64 + o+1)*J_ + j)*T_ + t] = (f1 - mf[o+1])*rfg[o+1] + fu_beta[o+1];
    }
}

// ---------------------------------------------------------------------------
extern "C" void kernel_launch(void* const* d_in, const int* in_sizes, int n_in,
                              void* d_out, int out_size, void* d_ws, size_t ws_size,
                              hipStream_t stream) {
    const float* x         = (const float*)d_in[0];
    const float* conv_w    = (const float*)d_in[1];
    const float* conv_b    = (const float*)d_in[2];
    const float* raw_gamma = (const float*)d_in[3];
    const float* raw_beta  = (const float*)d_in[4];
    const float* sp_W      = (const float*)d_in[5];
    const float* sp_b      = (const float*)d_in[6];
    const float* tp_W      = (const float*)d_in[7];
    const float* tp_b      = (const float*)d_in[8];
    const float* ps_w      = (const float*)d_in[9];
    const float* ps_b      = (const float*)d_in[10];
    const float* ps_gamma  = (const float*)d_in[11];
    const float* ps_beta   = (const float*)d_in[12];
    const float* fu_w      = (const float*)d_in[13];
    const float* fu_b      = (const float*)d_in[14];
    const float* fu_gamma  = (const float*)d_in[15];
    const float* fu_beta   = (const float*)d_in[16];
    const int*   neighbors = (const int*)d_in[17];

    char* ws = (char*)d_ws;
    unsigned short* zcat   = (unsigned short*)ws;                      // [N][128] bf16
    unsigned short* z_fu   = (unsigned short*)(ws + 104857600);        // [N][64] bf16
    size_t off = 157286400;
    float* wsig_t = (float*)(ws + off);          off += 168*64*4;      // [168][64] f32
    float* w12s_t = (float*)(ws + off);          off += 128*64*4;      // [128][64] f32
    unsigned short* w12h = (unsigned short*)(ws + off); off += 64*WST*2;
    unsigned short* w12l = (unsigned short*)(ws + off); off += 64*WST*2;
    float* f32s   = (float*)(ws + off);
    float* cb      = f32s;            // 64
    float* fb2     = f32s + 64;       // 64
    float* mf      = f32s + 128;      // 64
    float* rfg     = f32s + 192;      // 64
    float* sum_cp8 = f32s + 256;      // 8*128
    float* ssq_cp8 = f32s + 1280;     // 8*128
    float* sum_f8  = f32s + 2304;     // 8*64
    float* ssq_f8  = f32s + 2816;     // 8*64   (end: 3328 floats)

    hipMemsetAsync(sum_cp8, 0, 3072*sizeof(float), stream);

    k_prep<<<169, 64, 0, stream>>>(sp_W, sp_b, tp_W, tp_b, ps_w, ps_b, wsig_t, cb);
    k_sig<<<6400, 256, 0, stream>>>(x, neighbors, wsig_t, cb, conv_w, conv_b, zcat,
                                    sum_cp8, ssq_cp8);
    k_fin1<<<1, 64, 0, stream>>>(sum_cp8, ssq_cp8, raw_gamma, raw_beta,
                                 ps_gamma, ps_beta, fu_w, fu_b,
                                 w12h, w12l, w12s_t, fb2);
    k_fu<<<3200, 256, 0, stream>>>(zcat, w12h, w12l, w12s_t, fb2, z_fu,
                                   sum_f8, ssq_f8);
    k_fin2<<<1, 64, 0, stream>>>(sum_f8, ssq_f8, fu_gamma, mf, rfg);
    k_out<<<1600, 256, 0, stream>>>(z_fu, mf, rfg, fu_beta, (float*)d_out);
}

// Round 7
// 517.607 us; speedup vs baseline: 2.2381x; 2.2381x over previous
//
#include <hip/hip_runtime.h>
#include <hip/hip_bf16.h>
#include <stdint.h>

#define B_   64
#define C_   3
#define J_   25
#define T_   256
#define CO_  64
#define N_   (B_*J_*T_)     // 409600 locations, loc = (b*J_+j)*T_ + t
#define SIGD 84
#define FSTR 177            // feats LDS stride (f32) — (17*lt+k)%32: 2-way banks only
#define WST  136            // w12 bf16 row stride (elements), K=128 + 8 pad
#define NSLOT 32            // stat accumulation slots (atomic contention spreading)

typedef short   s16x8  __attribute__((ext_vector_type(8)));
typedef __bf16  bf16x8 __attribute__((ext_vector_type(8)));
typedef float   f32x4  __attribute__((ext_vector_type(4)));
typedef float   f32x2  __attribute__((ext_vector_type(2)));

__device__ __forceinline__ unsigned short f2b(float f) {
    unsigned int u = __float_as_uint(f);
    u += 0x7fffu + ((u >> 16) & 1u);          // round-to-nearest-even
    return (unsigned short)(u >> 16);
}
__device__ __forceinline__ float b2f(unsigned int bits_lo16) {
    return __uint_as_float(bits_lo16 << 16);
}
__device__ __forceinline__ unsigned int pack2(float a, float b) {
    return (unsigned int)f2b(a) | ((unsigned int)f2b(b) << 16);
}
__device__ __forceinline__ void split2(float f, unsigned short& h, unsigned short& l) {
    h = f2b(f);
    l = f2b(f - b2f((unsigned int)h));
}

// ---------------------------------------------------------------------------
// depth-3 signature of a 3-increment path in 4 dims (verified).
// ---------------------------------------------------------------------------
__device__ __forceinline__ void sig3(const float v0[4], const float v1[4],
                                     const float v2[4], float* __restrict__ S) {
    float* S1 = S;
    float* S2 = S + 4;
    float* S3 = S + 20;
    #pragma unroll
    for (int i = 0; i < 4; i++) S1[i] = v0[i];
    #pragma unroll
    for (int i = 0; i < 4; i++)
        #pragma unroll
        for (int j = 0; j < 4; j++) S2[i*4+j] = 0.5f * v0[i] * v0[j];
    #pragma unroll
    for (int i = 0; i < 4; i++)
        #pragma unroll
        for (int j = 0; j < 4; j++)
            #pragma unroll
            for (int k = 0; k < 4; k++)
                S3[i*16+j*4+k] = S2[i*4+j] * v0[k] * (1.f/3.f);

    #pragma unroll
    for (int s = 0; s < 2; s++) {
        const float* v = (s == 0) ? v1 : v2;
        float B2[16], v3[4];
        #pragma unroll
        for (int k = 0; k < 4; k++) v3[k] = v[k] * (1.f/3.f);
        #pragma unroll
        for (int i = 0; i < 4; i++)
            #pragma unroll
            for (int j = 0; j < 4; j++) B2[i*4+j] = 0.5f * v[i] * v[j];
        #pragma unroll
        for (int i = 0; i < 4; i++)
            #pragma unroll
            for (int j = 0; j < 4; j++)
                #pragma unroll
                for (int k = 0; k < 4; k++)
                    S3[i*16+j*4+k] += B2[i*4+j]*v3[k] + S1[i]*B2[j*4+k] + S2[i*4+j]*v[k];
        #pragma unroll
        for (int i = 0; i < 4; i++)
            #pragma unroll
            for (int j = 0; j < 4; j++) S2[i*4+j] += B2[i*4+j] + S1[i]*v[j];
        #pragma unroll
        for (int i = 0; i < 4; i++) S1[i] += v[i];
    }
}

// ---------------------------------------------------------------------------
// K0: fold signet weights through ps_w into f32 wsig_t[168][64] (k-major).
// grid=169 (k; 168=bias), block=64 (o).   (verified baseline)
// ---------------------------------------------------------------------------
__global__ void k_prep(const float* __restrict__ sp_W, const float* __restrict__ sp_b,
                       const float* __restrict__ tp_W, const float* __restrict__ tp_b,
                       const float* __restrict__ ps_w, const float* __restrict__ ps_b,
                       float* __restrict__ wsig_t, float* __restrict__ cb) {
    int k = blockIdx.x;
    int o = threadIdx.x;
    if (k < SIGD) {
        float v = 0.f;
        for (int i = 0; i < 64; i++) v += sp_W[k*64+i] * ps_w[o*128+i];
        wsig_t[k*64 + o] = v;
    } else if (k < 2*SIGD) {
        int m = k - SIGD;
        float v = 0.f;
        for (int i = 0; i < 64; i++) v += tp_W[m*64+i] * ps_w[o*128+64+i];
        wsig_t[k*64 + o] = v;
    } else {
        float a = ps_b[o];
        for (int i = 0; i < 64; i++)
            a += ps_w[o*128+i]*sp_b[i] + ps_w[o*128+64+i]*tp_b[i];
        cb[o] = a;
    }
}

// ---------------------------------------------------------------------------
// K1: fused conv1x3 + signatures + packed-f32 folded matvec (VERIFIED
// baseline) + register-resident stats: values are reduced via in-wave
// __shfl_xor butterflies while still in registers (NO global read-back),
// then 384 atomics/block spread over NSLOT slots.  Replaces k_stats<128>.
// Grid: 1600 (b,j) x 4 quarters, 64 locs/block.
// ---------------------------------------------------------------------------
__global__ __launch_bounds__(256) void k_sig(const float* __restrict__ x,
                                             const int* __restrict__ nbr,
                                             const float* __restrict__ wsig_t,
                                             const float* __restrict__ cb,
                                             const float* __restrict__ conv_w,
                                             const float* __restrict__ conv_b,
                                             unsigned short* __restrict__ zcat,
                                             float* __restrict__ sum_cp,
                                             float* __restrict__ ssq_cp) {
    __shared__ float feats[64*FSTR];   // 45312 B

    const int i       = threadIdx.x;
    const int quarter = blockIdx.x & 3;
    const int bj      = blockIdx.x >> 2;
    const int b       = bj / J_, j = bj % J_;
    const int loc_base = bj*T_ + quarter*64;
    const int slot = blockIdx.x & (NSLOT-1);

    if (i < 128) {
        const int lt   = i >> 1;
        const int path = i & 1;
        const int t    = quarter*64 + lt;
        float p0[4], p1[4], p2[4];
        p0[0] = 0.f; p1[0] = 0.5f; p2[0] = 1.0f;
        if (path == 0) {
            int n0 = nbr[j*3+0], n1 = nbr[j*3+1], n2 = nbr[j*3+2];
            #pragma unroll
            for (int c = 0; c < 3; c++) {
                const float* xc = x + ((size_t)(b*3+c)*J_)*T_ + t;
                p0[c+1] = xc[n0*T_];
                p1[c+1] = xc[n1*T_];
                p2[c+1] = xc[n2*T_];
            }
        } else {
            int tm = (t > 0)    ? t-1 : 0;
            int tp = (t < T_-1) ? t+1 : T_-1;
            #pragma unroll
            for (int c = 0; c < 3; c++) {
                const float* xr = x + ((size_t)(b*3+c)*J_ + j)*T_;
                p0[c+1] = xr[tm];
                p1[c+1] = xr[t];
                p2[c+1] = xr[tp];
            }
        }
        float v0[4], v1[4], v2[4];
        #pragma unroll
        for (int d = 0; d < 4; d++) { v0[d]=p0[d]; v1[d]=p1[d]-p0[d]; v2[d]=p2[d]-p1[d]; }
        float S[SIGD];
        sig3(v0, v1, v2, S);
        float* frow = feats + lt*FSTR + path*SIGD;
        #pragma unroll
        for (int m = 0; m < SIGD; m++) frow[m] = S[m];
    } else {
        // conv1x3 + relu -> zcat lower half, stats reduced from registers.
        const int ci  = i - 128;
        const int lt  = ci >> 1;
        const int chh = ci & 1;
        const int t   = quarter*64 + lt;
        const int loc = loc_base + lt;
        float xm[3], x0[3], xp[3];
        #pragma unroll
        for (int c = 0; c < 3; c++) {
            const float* xr = x + ((size_t)(b*3+c)*J_ + j)*T_;
            xm[c] = (t > 0)     ? xr[t-1] : 0.f;
            x0[c] = xr[t];
            xp[c] = (t < T_-1)  ? xr[t+1] : 0.f;
        }
        #pragma unroll
        for (int half = 0; half < 2; half++) {
            float v[16], q[16];
            unsigned int packed[8];
            #pragma unroll
            for (int oo2 = 0; oo2 < 8; oo2++) {
                float r[2];
                #pragma unroll
                for (int e = 0; e < 2; e++) {
                    int o = chh*32 + half*16 + oo2*2 + e;
                    float acc = conv_b[o];
                    #pragma unroll
                    for (int c = 0; c < 3; c++) {
                        const float* wr = conv_w + (o*3+c)*3;
                        acc += wr[0]*xm[c] + wr[1]*x0[c] + wr[2]*xp[c];
                    }
                    r[e] = fmaxf(acc, 0.f);
                    v[oo2*2+e] = r[e];
                }
                packed[oo2] = pack2(r[0], r[1]);
            }
            uint4* dst = (uint4*)(zcat + (size_t)loc*128 + chh*32 + half*16);
            dst[0] = make_uint4(packed[0], packed[1], packed[2], packed[3]);
            dst[1] = make_uint4(packed[4], packed[5], packed[6], packed[7]);
            // wave butterfly over the 32 locs of this wave (parity-preserving
            // offsets keep chh classes separate)
            #pragma unroll
            for (int k = 0; k < 16; k++) q[k] = v[k]*v[k];
            #pragma unroll
            for (int off = 2; off <= 32; off <<= 1) {
                #pragma unroll
                for (int k = 0; k < 16; k++) {
                    v[k] += __shfl_xor(v[k], off);
                    q[k] += __shfl_xor(q[k], off);
                }
            }
            if ((ci & 63) < 2) {      // one lane per chh per wave holds totals
                float* sb = sum_cp + slot*128 + chh*32 + half*16;
                float* qb = ssq_cp + slot*128 + chh*32 + half*16;
                #pragma unroll
                for (int k = 0; k < 16; k++) {
                    atomicAdd(sb + k, v[k]);
                    atomicAdd(qb + k, q[k]);
                }
            }
        }
    }
    __syncthreads();

    // ---- packed matvec: z_ps[loc][o] = relu(sum_k w[k][o]*f[loc][k]+cb) ----
    const int og = __builtin_amdgcn_readfirstlane(i >> 6);   // wave-uniform o-tile
    const int lt = i & 63;
    const int loc = loc_base + lt;
    const float* wt = wsig_t + og*16;        // + k*64
    f32x2 acc2[8];
    {
        const f32x2* cbp = (const f32x2*)(cb + og*16);
        #pragma unroll
        for (int p = 0; p < 8; p++) acc2[p] = cbp[p];
    }
    const float* frow = feats + lt*FSTR;
    #pragma unroll 4
    for (int k = 0; k < 2*SIGD; k++) {
        float f = frow[k];
        f32x2 f2 = { f, f };
        const f32x2* w2 = (const f32x2*)(wt + k*64);
        #pragma unroll
        for (int p = 0; p < 8; p++) acc2[p] += f2 * w2[p];   // v_pk_fma_f32
    }
    unsigned int pk[8];
    #pragma unroll
    for (int p = 0; p < 8; p++)
        pk[p] = pack2(fmaxf(acc2[p][0],0.f), fmaxf(acc2[p][1],0.f));
    uint4* dst = (uint4*)(zcat + (size_t)loc*128 + 64 + og*16);
    dst[0] = make_uint4(pk[0], pk[1], pk[2], pk[3]);
    dst[1] = make_uint4(pk[4], pk[5], pk[6], pk[7]);

    // ---- ps-channel stats from registers (wave all-reduce over 64 locs) ----
    {
        float v[16], q[16];
        #pragma unroll
        for (int p = 0; p < 8; p++) {
            v[2*p]   = fmaxf(acc2[p][0], 0.f);
            v[2*p+1] = fmaxf(acc2[p][1], 0.f);
        }
        #pragma unroll
        for (int k = 0; k < 16; k++) q[k] = v[k]*v[k];
        #pragma unroll
        for (int off = 1; off <= 32; off <<= 1) {
            #pragma unroll
            for (int k = 0; k < 16; k++) {
                v[k] += __shfl_xor(v[k], off);
                q[k] += __shfl_xor(q[k], off);
            }
        }
        if ((i & 63) == 0) {          // one lane per wave (16 channels each)
            float* sb = sum_cp + slot*128 + 64 + og*16;
            float* qb = ssq_cp + slot*128 + 64 + og*16;
            #pragma unroll
            for (int k = 0; k < 16; k++) {
                atomicAdd(sb + k, v[k]);
                atomicAdd(qb + k, q[k]);
            }
        }
    }
}

// ---------------------------------------------------------------------------
// K3: finalize conv/ps BN (NSLOT-slot sums); fold into fu weights.
// ---------------------------------------------------------------------------
__global__ void k_fin1(const float* __restrict__ sum_cp, const float* __restrict__ ssq_cp,
                       const float* __restrict__ raw_g, const float* __restrict__ raw_b,
                       const float* __restrict__ ps_g,  const float* __restrict__ ps_bt,
                       const float* __restrict__ fu_w,  const float* __restrict__ fu_b,
                       unsigned short* __restrict__ w12h, unsigned short* __restrict__ w12l,
                       float* __restrict__ w12s_t, float* __restrict__ fb2) {
    __shared__ float a[128], d[128];
    int i = threadIdx.x;    // 64
    const float inv = 1.f / (float)N_;
    float s0 = 0.f, q0 = 0.f, s1 = 0.f, q1 = 0.f;
    for (int sl = 0; sl < NSLOT; sl++) {
        s0 += sum_cp[sl*128 + i];       q0 += ssq_cp[sl*128 + i];
        s1 += sum_cp[sl*128 + 64 + i];  q1 += ssq_cp[sl*128 + 64 + i];
    }
    {
        float m = s0*inv, v = q0*inv - m*m;
        float sc = rsqrtf(v + 1e-5f) * raw_g[i];
        a[i] = sc; d[i] = raw_b[i] - m*sc;
    }
    {
        float m = s1*inv, v = q1*inv - m*m;
        float sc = rsqrtf(v + 1e-5f) * ps_g[i];
        a[64+i] = sc; d[64+i] = ps_bt[i] - m*sc;
    }
    __syncthreads();
    int o = i;
    float fb = fu_b[o];
    for (int k = 0; k < 128; k++) {
        float w = fu_w[o*128 + k];
        fb += w * d[k];
        float ws = w * a[k];
        w12s_t[k*64 + o] = ws;
        unsigned short h, l;
        split2(ws, h, l);
        w12h[o*WST + k] = h;
        w12l[o*WST + k] = l;
    }
    for (int k = 128; k < WST; k++) { w12h[o*WST + k] = 0; w12l[o*WST + k] = 0; }
    fb2[o] = fb;
}

// ---------------------------------------------------------------------------
// K4: fu GEMM via MFMA with in-kernel C/D-orientation probe (verified
// baseline) + stats post-pass (read-back verified in round 6) with LDS
// cross-wave combine + NSLOT-slot atomics.  Replaces k_stats<64>.
// ---------------------------------------------------------------------------
__global__ __launch_bounds__(256) void k_fu(const unsigned short* __restrict__ zcat,
                                            const unsigned short* __restrict__ w12h,
                                            const unsigned short* __restrict__ w12l,
                                            const float* __restrict__ w12s_t,
                                            const float* __restrict__ fb2,
                                            unsigned short* __restrict__ z_fu,
                                            float* __restrict__ sum_f,
                                            float* __restrict__ ssq_f) {
    __shared__ __align__(16) unsigned short zt[128*WST];   // 34816 B
    const int i = threadIdx.x;
    const int loc_base = blockIdx.x * 128;

    for (int c = i; c < 2048; c += 256) {
        int row = c >> 4, k = c & 15;
        s16x8 v = *(const s16x8*)(zcat + (size_t)(loc_base + row)*128 + k*8);
        *(s16x8*)(zt + row*WST + k*8) = v;
    }
    __syncthreads();

    const int lane = i & 63, wv = i >> 6;
    const int mrow = lane & 15, q = lane >> 4;
    const f32x4 zero = {0.f, 0.f, 0.f, 0.f};

    // ---- layout probe ----
    bf16x8 ap, bp;
    #pragma unroll
    for (int jj = 0; jj < 8; jj++) { ap[jj] = (__bf16)(float)mrow; bp[jj] = (__bf16)1.0f; }
    f32x4 pv = __builtin_amdgcn_mfma_f32_16x16x32_bf16(ap, bp, zero, 0, 0, 0);
    bool cC = true, cT = true;
    #pragma unroll
    for (int r = 0; r < 4; r++) {
        cC = cC && (pv[r] == 32.f*(float)(q*4 + r));
        cT = cT && (pv[r] == 32.f*(float)mrow);
    }
    const bool okC = (__ballot(cC) == ~0ull);
    const bool okT = (!okC) && (__ballot(cT) == ~0ull);

    if (okC || okT) {
        bf16x8 ah[4], al[4];
        {
            const unsigned short* arh = w12h + (size_t)(wv*16 + mrow)*WST + q*8;
            const unsigned short* arl = w12l + (size_t)(wv*16 + mrow)*WST + q*8;
            #pragma unroll
            for (int s = 0; s < 4; s++) {
                ah[s] = __builtin_bit_cast(bf16x8, *(const s16x8*)(arh + s*32));
                al[s] = __builtin_bit_cast(bf16x8, *(const s16x8*)(arl + s*32));
            }
        }
        f32x4 accs[8];
        #pragma unroll
        for (int lt8 = 0; lt8 < 8; lt8++) {
            const unsigned short* brow = zt + (size_t)(lt8*16 + mrow)*WST + q*8;
            f32x4 acc = zero;
            #pragma unroll
            for (int s = 0; s < 4; s++) {
                bf16x8 bfrag = __builtin_bit_cast(bf16x8, *(const s16x8*)(brow + s*32));
                acc = __builtin_amdgcn_mfma_f32_16x16x32_bf16(ah[s], bfrag, acc, 0, 0, 0);
                acc = __builtin_amdgcn_mfma_f32_16x16x32_bf16(al[s], bfrag, acc, 0, 0, 0);
            }
            accs[lt8] = acc;
        }
        __syncthreads();

        unsigned short* ot = zt;       // alias as [128 loc][72 o]
        if (okC) {
            const float4 fbv = *(const float4*)(fb2 + wv*16 + q*4);
            #pragma unroll
            for (int lt8 = 0; lt8 < 8; lt8++) {
                int row = lt8*16 + mrow;
                int o   = wv*16 + q*4;
                uint2 w;
                w.x = pack2(fmaxf(accs[lt8][0]+fbv.x,0.f), fmaxf(accs[lt8][1]+fbv.y,0.f));
                w.y = pack2(fmaxf(accs[lt8][2]+fbv.z,0.f), fmaxf(accs[lt8][3]+fbv.w,0.f));
                *(uint2*)(ot + row*72 + o) = w;
            }
        } else {
            const float fb1 = fb2[wv*16 + mrow];
            #pragma unroll
            for (int lt8 = 0; lt8 < 8; lt8++) {
                #pragma unroll
                for (int r = 0; r < 4; r++) {
                    int row = lt8*16 + q*4 + r;
                    ot[row*72 + wv*16 + mrow] = f2b(fmaxf(accs[lt8][r]+fb1, 0.f));
                }
            }
        }
        __syncthreads();
        for (int c = i; c < 1024; c += 256) {
            int row = c >> 3, k = c & 7;
            s16x8 v = *(const s16x8*)(ot + row*72 + k*8);
            *(s16x8*)(z_fu + (size_t)(loc_base + row)*64 + k*8) = v;
        }
    } else {
        // ---- scalar fallback (correctness net; slow but exact) ----
        if (i < 128) {
            const unsigned short* fr = zt + i*WST;
            const int loc = loc_base + i;
            for (int og8 = 0; og8 < 8; og8++) {
                float acc[8];
                #pragma unroll
                for (int p = 0; p < 8; p++) acc[p] = fb2[og8*8 + p];
                for (int k = 0; k < 128; k++) {
                    float f = b2f(fr[k]);
                    const float* w = w12s_t + k*64 + og8*8;
                    #pragma unroll
                    for (int p = 0; p < 8; p++) acc[p] = fmaf(f, w[p], acc[p]);
                }
                #pragma unroll
                for (int p = 0; p < 8; p++)
                    z_fu[(size_t)loc*64 + og8*8 + p] = f2b(fmaxf(acc[p], 0.f));
            }
        }
    }

    // ---- stats post-pass: L2-hot read-back (verified r6), LDS combine, ----
    // ---- NSLOT-spread atomics (128/block over 2048 addresses)          ----
    __syncthreads();        // z_fu stores drained; zt reads finished -> reuse
    {
        const int g3  = i & 7;           // 8 channel-groups of 8
        const int lr3 = i >> 3;          // wave wv covers rows wv*8..+7 (+32,64,96)
        float s[8], q2[8];
        #pragma unroll
        for (int k = 0; k < 8; k++) { s[k] = 0.f; q2[k] = 0.f; }
        #pragma unroll
        for (int li = 0; li < 4; li++) {
            const int l = lr3 + li*32;
            const uint4 v = *(const uint4*)(z_fu + (size_t)(loc_base + l)*64 + g3*8);
            unsigned int u[4] = { v.x, v.y, v.z, v.w };
            #pragma unroll
            for (int k = 0; k < 4; k++) {
                float f0 = b2f(u[k] & 0xffffu);
                float f1 = __uint_as_float(u[k] & 0xffff0000u);
                s[2*k]   += f0;  q2[2*k]   += f0*f0;
                s[2*k+1] += f1;  q2[2*k+1] += f1*f1;
            }
        }
        #pragma unroll
        for (int off = 8; off <= 32; off <<= 1) {
            #pragma unroll
            for (int k = 0; k < 8; k++) {
                s[k]  += __shfl_xor(s[k],  off);
                q2[k] += __shfl_xor(q2[k], off);
            }
        }
        float* red = (float*)zt;         // [4 wv][8 g][16] = 512 floats
        if (lane < 8) {                  // lane == g3 here
            #pragma unroll
            for (int k = 0; k < 8; k++) {
                red[(wv*8 + g3)*16 + k]     = s[k];
                red[(wv*8 + g3)*16 + 8 + k] = q2[k];
            }
        }
        __syncthreads();
        if (i < 128) {
            const int ch = i >> 1, which = i & 1;
            const int g = ch >> 3, k = ch & 7;
            const int idx = which*8 + k;
            float t0 = red[(0*8+g)*16 + idx] + red[(1*8+g)*16 + idx]
                     + red[(2*8+g)*16 + idx] + red[(3*8+g)*16 + idx];
            const int slot = blockIdx.x & (NSLOT-1);
            atomicAdd((which ? ssq_f : sum_f) + slot*64 + ch, t0);
        }
    }
}

// ---------------------------------------------------------------------------
// K5: finalize fu BN stats (NSLOT-slot sums)
// ---------------------------------------------------------------------------
__global__ void k_fin2(const float* __restrict__ sum_f, const float* __restrict__ ssq_f,
                       const float* __restrict__ fu_g,
                       float* __restrict__ mf, float* __restrict__ rfg) {
    int o = threadIdx.x;
    const float inv = 1.f / (float)N_;
    float sm = 0.f, sq = 0.f;
    for (int sl = 0; sl < NSLOT; sl++) { sm += sum_f[sl*64 + o]; sq += ssq_f[sl*64 + o]; }
    float m = sm*inv, v = sq*inv - m*m;
    mf[o] = m;
    rfg[o] = rsqrtf(v + 1e-5f) * fu_g[o];
}

// ---------------------------------------------------------------------------
// K6: apply fu BN, transpose [loc][64] -> out [b][o][j][t] f32. (unchanged)
// ---------------------------------------------------------------------------
__global__ __launch_bounds__(256) void k_out(const unsigned short* __restrict__ z_fu,
                                             const float* __restrict__ mf,
                                             const float* __restrict__ rfg,
                                             const float* __restrict__ fu_beta,
                                             float* __restrict__ out) {
    __shared__ __align__(16) unsigned short zt[256*66];
    const int i = threadIdx.x;
    const int bj = blockIdx.x;
    const int b = bj / J_, j = bj % J_;
    const int loc_base = bj * T_;

    for (int c = i; c < 2048; c += 256) {
        int row = c >> 3, k = c & 7;
        uint4 v = *(const uint4*)(z_fu + (size_t)(loc_base + row)*64 + k*8);
        unsigned int* dst = (unsigned int*)(zt + row*66 + k*8);
        dst[0] = v.x; dst[1] = v.y; dst[2] = v.z; dst[3] = v.w;
    }
    __syncthreads();

    const int t = i;
    const unsigned int* zrow = (const unsigned int*)zt + t*33;
    for (int o = 0; o < 64; o += 2) {
        unsigned int v = zrow[o >> 1];
        float f0 = b2f(v & 0xffffu);
        float f1 = __uint_as_float(v & 0xffff0000u);
        out[(((size_t)b*64 + o  )*J_ + j)*T_ + t] = (f0 - mf[o  ])*rfg[o  ] + fu_beta[o  ];
        out[(((size_t)b*64 + o+1)*J_ + j)*T_ + t] = (f1 - mf[o+1])*rfg[o+1] + fu_beta[o+1];
    }
}

// ---------------------------------------------------------------------------
extern "C" void kernel_launch(void* const* d_in, const int* in_sizes, int n_in,
                              void* d_out, int out_size, void* d_ws, size_t ws_size,
                              hipStream_t stream) {
    const float* x         = (const float*)d_in[0];
    const float* conv_w    = (const float*)d_in[1];
    const float* conv_b    = (const float*)d_in[2];
    const float* raw_gamma = (const float*)d_in[3];
    const float* raw_beta  = (const float*)d_in[4];
    const float* sp_W      = (const float*)d_in[5];
    const float* sp_b      = (const float*)d_in[6];
    const float* tp_W      = (const float*)d_in[7];
    const float* tp_b      = (const float*)d_in[8];
    const float* ps_w      = (const float*)d_in[9];
    const float* ps_b      = (const float*)d_in[10];
    const float* ps_gamma  = (const float*)d_in[11];
    const float* ps_beta   = (const float*)d_in[12];
    const float* fu_w      = (const float*)d_in[13];
    const float* fu_b      = (const float*)d_in[14];
    const float* fu_gamma  = (const float*)d_in[15];
    const float* fu_beta   = (const float*)d_in[16];
    const int*   neighbors = (const int*)d_in[17];

    char* ws = (char*)d_ws;
    unsigned short* zcat   = (unsigned short*)ws;                      // [N][128] bf16
    unsigned short* z_fu   = (unsigned short*)(ws + 104857600);        // [N][64] bf16
    size_t off = 157286400;
    float* wsig_t = (float*)(ws + off);          off += 168*64*4;      // [168][64] f32
    float* w12s_t = (float*)(ws + off);          off += 128*64*4;      // [128][64] f32
    unsigned short* w12h = (unsigned short*)(ws + off); off += 64*WST*2;
    unsigned short* w12l = (unsigned short*)(ws + off); off += 64*WST*2;
    float* f32s   = (float*)(ws + off);
    float* cb     = f32s;                         // 64
    float* fb2    = f32s + 64;                    // 64
    float* mf     = f32s + 128;                   // 64
    float* rfg    = f32s + 192;                   // 64
    float* sum_cp = f32s + 256;                   // NSLOT*128
    float* ssq_cp = sum_cp + NSLOT*128;           // NSLOT*128
    float* sum_f  = ssq_cp + NSLOT*128;           // NSLOT*64
    float* ssq_f  = sum_f  + NSLOT*64;            // NSLOT*64

    hipMemsetAsync(sum_cp, 0, (size_t)NSLOT*(128+128+64+64)*sizeof(float), stream);

    k_prep<<<169, 64, 0, stream>>>(sp_W, sp_b, tp_W, tp_b, ps_w, ps_b, wsig_t, cb);
    k_sig<<<6400, 256, 0, stream>>>(x, neighbors, wsig_t, cb, conv_w, conv_b, zcat,
                                    sum_cp, ssq_cp);
    k_fin1<<<1, 64, 0, stream>>>(sum_cp, ssq_cp, raw_gamma, raw_beta,
                                 ps_gamma, ps_beta, fu_w, fu_b,
                                 w12h, w12l, w12s_t, fb2);
    k_fu<<<3200, 256, 0, stream>>>(zcat, w12h, w12l, w12s_t, fb2, z_fu,
                                   sum_f, ssq_f);
    k_fin2<<<1, 64, 0, stream>>>(sum_f, ssq_f, fu_gamma, mf, rfg);
    k_out<<<1600, 256, 0, stream>>>(z_fu, mf, rfg, fu_beta, (float*)d_out);
}

// Round 8
// 461.147 us; speedup vs baseline: 2.5121x; 1.1224x over previous
//
#include <hip/hip_runtime.h>
#include <hip/hip_bf16.h>
#include <stdint.h>

#define B_   64
#define C_   3
#define J_   25
#define T_   256
#define CO_  64
#define N_   (B_*J_*T_)     // 409600 locations, loc = (b*J_+j)*T_ + t
#define SIGD 84
#define FSTR 177            // feats LDS stride (f32) — (17*lt+k)%32: 2-way banks only
#define WST  136            // w12 bf16 row stride (elements), K=128 + 8 pad
#define NSLOT 32            // f-stat slots (k_fu post-pass, verified r7)
#define NRED 64             // k_red1 grid (second-level partials)

typedef short   s16x8  __attribute__((ext_vector_type(8)));
typedef __bf16  bf16x8 __attribute__((ext_vector_type(8)));
typedef float   f32x4  __attribute__((ext_vector_type(4)));
typedef float   f32x2  __attribute__((ext_vector_type(2)));

__device__ __forceinline__ unsigned short f2b(float f) {
    unsigned int u = __float_as_uint(f);
    u += 0x7fffu + ((u >> 16) & 1u);          // round-to-nearest-even
    return (unsigned short)(u >> 16);
}
__device__ __forceinline__ float b2f(unsigned int bits_lo16) {
    return __uint_as_float(bits_lo16 << 16);
}
__device__ __forceinline__ unsigned int pack2(float a, float b) {
    return (unsigned int)f2b(a) | ((unsigned int)f2b(b) << 16);
}
__device__ __forceinline__ void split2(float f, unsigned short& h, unsigned short& l) {
    h = f2b(f);
    l = f2b(f - b2f((unsigned int)h));
}

// ---------------------------------------------------------------------------
// depth-3 signature of a 3-increment path in 4 dims (verified).
// ---------------------------------------------------------------------------
__device__ __forceinline__ void sig3(const float v0[4], const float v1[4],
                                     const float v2[4], float* __restrict__ S) {
    float* S1 = S;
    float* S2 = S + 4;
    float* S3 = S + 20;
    #pragma unroll
    for (int i = 0; i < 4; i++) S1[i] = v0[i];
    #pragma unroll
    for (int i = 0; i < 4; i++)
        #pragma unroll
        for (int j = 0; j < 4; j++) S2[i*4+j] = 0.5f * v0[i] * v0[j];
    #pragma unroll
    for (int i = 0; i < 4; i++)
        #pragma unroll
        for (int j = 0; j < 4; j++)
            #pragma unroll
            for (int k = 0; k < 4; k++)
                S3[i*16+j*4+k] = S2[i*4+j] * v0[k] * (1.f/3.f);

    #pragma unroll
    for (int s = 0; s < 2; s++) {
        const float* v = (s == 0) ? v1 : v2;
        float B2[16], v3[4];
        #pragma unroll
        for (int k = 0; k < 4; k++) v3[k] = v[k] * (1.f/3.f);
        #pragma unroll
        for (int i = 0; i < 4; i++)
            #pragma unroll
            for (int j = 0; j < 4; j++) B2[i*4+j] = 0.5f * v[i] * v[j];
        #pragma unroll
        for (int i = 0; i < 4; i++)
            #pragma unroll
            for (int j = 0; j < 4; j++)
                #pragma unroll
                for (int k = 0; k < 4; k++)
                    S3[i*16+j*4+k] += B2[i*4+j]*v3[k] + S1[i]*B2[j*4+k] + S2[i*4+j]*v[k];
        #pragma unroll
        for (int i = 0; i < 4; i++)
            #pragma unroll
            for (int j = 0; j < 4; j++) S2[i*4+j] += B2[i*4+j] + S1[i]*v[j];
        #pragma unroll
        for (int i = 0; i < 4; i++) S1[i] += v[i];
    }
}

// ---------------------------------------------------------------------------
// K0: fold signet weights through ps_w into f32 wsig_t[168][64] (k-major).
// grid=169 (k; 168=bias), block=64 (o).   (verified baseline)
// ---------------------------------------------------------------------------
__global__ void k_prep(const float* __restrict__ sp_W, const float* __restrict__ sp_b,
                       const float* __restrict__ tp_W, const float* __restrict__ tp_b,
                       const float* __restrict__ ps_w, const float* __restrict__ ps_b,
                       float* __restrict__ wsig_t, float* __restrict__ cb) {
    int k = blockIdx.x;
    int o = threadIdx.x;
    if (k < SIGD) {
        float v = 0.f;
        for (int i = 0; i < 64; i++) v += sp_W[k*64+i] * ps_w[o*128+i];
        wsig_t[k*64 + o] = v;
    } else if (k < 2*SIGD) {
        int m = k - SIGD;
        float v = 0.f;
        for (int i = 0; i < 64; i++) v += tp_W[m*64+i] * ps_w[o*128+64+i];
        wsig_t[k*64 + o] = v;
    } else {
        float a = ps_b[o];
        for (int i = 0; i < 64; i++)
            a += ps_w[o*128+i]*sp_b[i] + ps_w[o*128+64+i]*tp_b[i];
        cb[o] = a;
    }
}

// ---------------------------------------------------------------------------
// K1: fused conv1x3 + signatures + packed-f32 folded matvec (VERIFIED) +
// register-resident stats (r7-verified butterflies) combined via a 1.5 KB
// LDS scratch and emitted as ONE plain coalesced 1 KB row per block:
// partial[bid][256] (cs = which*128 + ch).  ZERO atomics (r7 showed 2.46M
// atomics -> +77MB write-through + ~110us TCC serialization).
// Grid: 1600 (b,j) x 4 quarters, 64 locs/block.
// ---------------------------------------------------------------------------
__global__ __launch_bounds__(256) void k_sig(const float* __restrict__ x,
                                             const int* __restrict__ nbr,
                                             const float* __restrict__ wsig_t,
                                             const float* __restrict__ cb,
                                             const float* __restrict__ conv_w,
                                             const float* __restrict__ conv_b,
                                             unsigned short* __restrict__ zcat,
                                             float* __restrict__ partial) {
    __shared__ float feats[64*FSTR];   // 45312 B
    __shared__ float sred[384];        // [2 conv-wave][2 which][64 ch] + [4 og][32]

    const int i       = threadIdx.x;
    const int quarter = blockIdx.x & 3;
    const int bj      = blockIdx.x >> 2;
    const int b       = bj / J_, j = bj % J_;
    const int loc_base = bj*T_ + quarter*64;

    if (i < 128) {
        const int lt   = i >> 1;
        const int path = i & 1;
        const int t    = quarter*64 + lt;
        float p0[4], p1[4], p2[4];
        p0[0] = 0.f; p1[0] = 0.5f; p2[0] = 1.0f;
        if (path == 0) {
            int n0 = nbr[j*3+0], n1 = nbr[j*3+1], n2 = nbr[j*3+2];
            #pragma unroll
            for (int c = 0; c < 3; c++) {
                const float* xc = x + ((size_t)(b*3+c)*J_)*T_ + t;
                p0[c+1] = xc[n0*T_];
                p1[c+1] = xc[n1*T_];
                p2[c+1] = xc[n2*T_];
            }
        } else {
            int tm = (t > 0)    ? t-1 : 0;
            int tp = (t < T_-1) ? t+1 : T_-1;
            #pragma unroll
            for (int c = 0; c < 3; c++) {
                const float* xr = x + ((size_t)(b*3+c)*J_ + j)*T_;
                p0[c+1] = xr[tm];
                p1[c+1] = xr[t];
                p2[c+1] = xr[tp];
            }
        }
        float v0[4], v1[4], v2[4];
        #pragma unroll
        for (int d = 0; d < 4; d++) { v0[d]=p0[d]; v1[d]=p1[d]-p0[d]; v2[d]=p2[d]-p1[d]; }
        float S[SIGD];
        sig3(v0, v1, v2, S);
        float* frow = feats + lt*FSTR + path*SIGD;
        #pragma unroll
        for (int m = 0; m < SIGD; m++) frow[m] = S[m];
    } else {
        // conv1x3 + relu -> zcat lower half; stats reduced from registers.
        const int ci  = i - 128;
        const int lt  = ci >> 1;
        const int chh = ci & 1;
        const int w   = ci >> 6;       // conv wave (0: locs 0-31, 1: locs 32-63)
        const int t   = quarter*64 + lt;
        const int loc = loc_base + lt;
        float xm[3], x0[3], xp[3];
        #pragma unroll
        for (int c = 0; c < 3; c++) {
            const float* xr = x + ((size_t)(b*3+c)*J_ + j)*T_;
            xm[c] = (t > 0)     ? xr[t-1] : 0.f;
            x0[c] = xr[t];
            xp[c] = (t < T_-1)  ? xr[t+1] : 0.f;
        }
        #pragma unroll
        for (int half = 0; half < 2; half++) {
            float v[16], q[16];
            unsigned int packed[8];
            #pragma unroll
            for (int oo2 = 0; oo2 < 8; oo2++) {
                float r[2];
                #pragma unroll
                for (int e = 0; e < 2; e++) {
                    int o = chh*32 + half*16 + oo2*2 + e;
                    float acc = conv_b[o];
                    #pragma unroll
                    for (int c = 0; c < 3; c++) {
                        const float* wr = conv_w + (o*3+c)*3;
                        acc += wr[0]*xm[c] + wr[1]*x0[c] + wr[2]*xp[c];
                    }
                    r[e] = fmaxf(acc, 0.f);
                    v[oo2*2+e] = r[e];
                }
                packed[oo2] = pack2(r[0], r[1]);
            }
            uint4* dst = (uint4*)(zcat + (size_t)loc*128 + chh*32 + half*16);
            dst[0] = make_uint4(packed[0], packed[1], packed[2], packed[3]);
            dst[1] = make_uint4(packed[4], packed[5], packed[6], packed[7]);
            // wave butterfly over this wave's 32 locs (parity-preserving:
            // chh classes stay separate) — verified r7
            #pragma unroll
            for (int k = 0; k < 16; k++) q[k] = v[k]*v[k];
            #pragma unroll
            for (int off = 2; off <= 32; off <<= 1) {
                #pragma unroll
                for (int k = 0; k < 16; k++) {
                    v[k] += __shfl_xor(v[k], off);
                    q[k] += __shfl_xor(q[k], off);
                }
            }
            if ((ci & 63) < 2) {      // lane 0 holds chh=0 totals, lane 1 chh=1
                #pragma unroll
                for (int k = 0; k < 16; k++) {
                    sred[w*128 + chh*32 + half*16 + k]      = v[k];
                    sred[w*128 + 64 + chh*32 + half*16 + k] = q[k];
                }
            }
        }
    }
    __syncthreads();

    // ---- packed matvec: z_ps[loc][o] = relu(sum_k w[k][o]*f[loc][k]+cb) ----
    const int og = __builtin_amdgcn_readfirstlane(i >> 6);   // wave-uniform o-tile
    const int lt = i & 63;
    const int loc = loc_base + lt;
    const float* wt = wsig_t + og*16;        // + k*64
    f32x2 acc2[8];
    {
        const f32x2* cbp = (const f32x2*)(cb + og*16);
        #pragma unroll
        for (int p = 0; p < 8; p++) acc2[p] = cbp[p];
    }
    const float* frow = feats + lt*FSTR;
    #pragma unroll 4
    for (int k = 0; k < 2*SIGD; k++) {
        float f = frow[k];
        f32x2 f2 = { f, f };
        const f32x2* w2 = (const f32x2*)(wt + k*64);
        #pragma unroll
        for (int p = 0; p < 8; p++) acc2[p] += f2 * w2[p];   // v_pk_fma_f32
    }
    unsigned int pk[8];
    #pragma unroll
    for (int p = 0; p < 8; p++)
        pk[p] = pack2(fmaxf(acc2[p][0],0.f), fmaxf(acc2[p][1],0.f));
    uint4* dst = (uint4*)(zcat + (size_t)loc*128 + 64 + og*16);
    dst[0] = make_uint4(pk[0], pk[1], pk[2], pk[3]);
    dst[1] = make_uint4(pk[4], pk[5], pk[6], pk[7]);

    // ---- ps-channel stats from registers (full-wave butterfly, r7) ----
    {
        float v[16], q[16];
        #pragma unroll
        for (int p = 0; p < 8; p++) {
            v[2*p]   = fmaxf(acc2[p][0], 0.f);
            v[2*p+1] = fmaxf(acc2[p][1], 0.f);
        }
        #pragma unroll
        for (int k = 0; k < 16; k++) q[k] = v[k]*v[k];
        #pragma unroll
        for (int off = 1; off <= 32; off <<= 1) {
            #pragma unroll
            for (int k = 0; k < 16; k++) {
                v[k] += __shfl_xor(v[k], off);
                q[k] += __shfl_xor(q[k], off);
            }
        }
        if ((i & 63) == 0) {          // one lane per wave (16 channels each)
            #pragma unroll
            for (int k = 0; k < 16; k++) {
                sred[256 + og*32 + k]      = v[k];
                sred[256 + og*32 + 16 + k] = q[k];
            }
        }
    }
    __syncthreads();

    // ---- one coalesced 1KB partial row per block (NO atomics) ----
    {
        const int which = i >> 7, ch = i & 127;   // cs = which*128 + ch = i
        float val;
        if (ch < 64) {
            val = sred[which*64 + ch] + sred[128 + which*64 + ch];
        } else {
            const int cp = ch - 64;
            val = sred[256 + (cp >> 4)*32 + which*16 + (cp & 15)];
        }
        partial[(size_t)blockIdx.x*256 + i] = val;
    }
}

// ---------------------------------------------------------------------------
// K2: second-level reduce of partial[6400][256] -> red2[NRED][256].
// Coalesced 1KB rows; 100 rows/block; plain stores (no atomics).
// ---------------------------------------------------------------------------
__global__ __launch_bounds__(256) void k_red1(const float* __restrict__ partial,
                                              float* __restrict__ red2) {
    const int t = threadIdx.x;
    float acc = 0.f;
    for (int r = blockIdx.x; r < 6400; r += NRED)
        acc += partial[(size_t)r*256 + t];
    red2[blockIdx.x*256 + t] = acc;
}

// ---------------------------------------------------------------------------
// K3: finalize conv/ps BN (NRED-slot sums); fold into fu weights.
// ---------------------------------------------------------------------------
__global__ void k_fin1(const float* __restrict__ red2,
                       const float* __restrict__ raw_g, const float* __restrict__ raw_b,
                       const float* __restrict__ ps_g,  const float* __restrict__ ps_bt,
                       const float* __restrict__ fu_w,  const float* __restrict__ fu_b,
                       unsigned short* __restrict__ w12h, unsigned short* __restrict__ w12l,
                       float* __restrict__ w12s_t, float* __restrict__ fb2) {
    __shared__ float a[128], d[128];
    int i = threadIdx.x;    // 64
    const float inv = 1.f / (float)N_;
    float s0 = 0.f, q0 = 0.f, s1 = 0.f, q1 = 0.f;
    for (int sl = 0; sl < NRED; sl++) {
        const float* rr = red2 + sl*256;
        s0 += rr[i];        q0 += rr[128 + i];        // conv ch i
        s1 += rr[64 + i];   q1 += rr[192 + i];        // ps ch 64+i
    }
    {
        float m = s0*inv, v = q0*inv - m*m;
        float sc = rsqrtf(v + 1e-5f) * raw_g[i];
        a[i] = sc; d[i] = raw_b[i] - m*sc;
    }
    {
        float m = s1*inv, v = q1*inv - m*m;
        float sc = rsqrtf(v + 1e-5f) * ps_g[i];
        a[64+i] = sc; d[64+i] = ps_bt[i] - m*sc;
    }
    __syncthreads();
    int o = i;
    float fb = fu_b[o];
    for (int k = 0; k < 128; k++) {
        float w = fu_w[o*128 + k];
        fb += w * d[k];
        float ws = w * a[k];
        w12s_t[k*64 + o] = ws;
        unsigned short h, l;
        split2(ws, h, l);
        w12h[o*WST + k] = h;
        w12l[o*WST + k] = l;
    }
    for (int k = 128; k < WST; k++) { w12h[o*WST + k] = 0; w12l[o*WST + k] = 0; }
    fb2[o] = fb;
}

// ---------------------------------------------------------------------------
// K4: fu GEMM via MFMA with in-kernel C/D-orientation probe (verified
// baseline) + stats post-pass with LDS combine + NSLOT atomics (verified r7:
// 410K atomics over 2048 addrs is cheap at this scale).
// ---------------------------------------------------------------------------
__global__ __launch_bounds__(256) void k_fu(const unsigned short* __restrict__ zcat,
                                            const unsigned short* __restrict__ w12h,
                                            const unsigned short* __restrict__ w12l,
                                            const float* __restrict__ w12s_t,
                                            const float* __restrict__ fb2,
                                            unsigned short* __restrict__ z_fu,
                                            float* __restrict__ sum_f,
                                            float* __restrict__ ssq_f) {
    __shared__ __align__(16) unsigned short zt[128*WST];   // 34816 B
    const int i = threadIdx.x;
    const int loc_base = blockIdx.x * 128;

    for (int c = i; c < 2048; c += 256) {
        int row = c >> 4, k = c & 15;
        s16x8 v = *(const s16x8*)(zcat + (size_t)(loc_base + row)*128 + k*8);
        *(s16x8*)(zt + row*WST + k*8) = v;
    }
    __syncthreads();

    const int lane = i & 63, wv = i >> 6;
    const int mrow = lane & 15, q = lane >> 4;
    const f32x4 zero = {0.f, 0.f, 0.f, 0.f};

    // ---- layout probe ----
    bf16x8 ap, bp;
    #pragma unroll
    for (int jj = 0; jj < 8; jj++) { ap[jj] = (__bf16)(float)mrow; bp[jj] = (__bf16)1.0f; }
    f32x4 pv = __builtin_amdgcn_mfma_f32_16x16x32_bf16(ap, bp, zero, 0, 0, 0);
    bool cC = true, cT = true;
    #pragma unroll
    for (int r = 0; r < 4; r++) {
        cC = cC && (pv[r] == 32.f*(float)(q*4 + r));
        cT = cT && (pv[r] == 32.f*(float)mrow);
    }
    const bool okC = (__ballot(cC) == ~0ull);
    const bool okT = (!okC) && (__ballot(cT) == ~0ull);

    if (okC || okT) {
        bf16x8 ah[4], al[4];
        {
            const unsigned short* arh = w12h + (size_t)(wv*16 + mrow)*WST + q*8;
            const unsigned short* arl = w12l + (size_t)(wv*16 + mrow)*WST + q*8;
            #pragma unroll
            for (int s = 0; s < 4; s++) {
                ah[s] = __builtin_bit_cast(bf16x8, *(const s16x8*)(arh + s*32));
                al[s] = __builtin_bit_cast(bf16x8, *(const s16x8*)(arl + s*32));
            }
        }
        f32x4 accs[8];
        #pragma unroll
        for (int lt8 = 0; lt8 < 8; lt8++) {
            const unsigned short* brow = zt + (size_t)(lt8*16 + mrow)*WST + q*8;
            f32x4 acc = zero;
            #pragma unroll
            for (int s = 0; s < 4; s++) {
                bf16x8 bfrag = __builtin_bit_cast(bf16x8, *(const s16x8*)(brow + s*32));
                acc = __builtin_amdgcn_mfma_f32_16x16x32_bf16(ah[s], bfrag, acc, 0, 0, 0);
                acc = __builtin_amdgcn_mfma_f32_16x16x32_bf16(al[s], bfrag, acc, 0, 0, 0);
            }
            accs[lt8] = acc;
        }
        __syncthreads();

        unsigned short* ot = zt;       // alias as [128 loc][72 o]
        if (okC) {
            const float4 fbv = *(const float4*)(fb2 + wv*16 + q*4);
            #pragma unroll
            for (int lt8 = 0; lt8 < 8; lt8++) {
                int row = lt8*16 + mrow;
                int o   = wv*16 + q*4;
                uint2 w;
                w.x = pack2(fmaxf(accs[lt8][0]+fbv.x,0.f), fmaxf(accs[lt8][1]+fbv.y,0.f));
                w.y = pack2(fmaxf(accs[lt8][2]+fbv.z,0.f), fmaxf(accs[lt8][3]+fbv.w,0.f));
                *(uint2*)(ot + row*72 + o) = w;
            }
        } else {
            const float fb1 = fb2[wv*16 + mrow];
            #pragma unroll
            for (int lt8 = 0; lt8 < 8; lt8++) {
                #pragma unroll
                for (int r = 0; r < 4; r++) {
                    int row = lt8*16 + q*4 + r;
                    ot[row*72 + wv*16 + mrow] = f2b(fmaxf(accs[lt8][r]+fb1, 0.f));
                }
            }
        }
        __syncthreads();
        for (int c = i; c < 1024; c += 256) {
            int row = c >> 3, k = c & 7;
            s16x8 v = *(const s16x8*)(ot + row*72 + k*8);
            *(s16x8*)(z_fu + (size_t)(loc_base + row)*64 + k*8) = v;
        }
    } else {
        // ---- scalar fallback (correctness net; slow but exact) ----
        if (i < 128) {
            const unsigned short* fr = zt + i*WST;
            const int loc = loc_base + i;
            for (int og8 = 0; og8 < 8; og8++) {
                float acc[8];
                #pragma unroll
                for (int p = 0; p < 8; p++) acc[p] = fb2[og8*8 + p];
                for (int k = 0; k < 128; k++) {
                    float f = b2f(fr[k]);
                    const float* w = w12s_t + k*64 + og8*8;
                    #pragma unroll
                    for (int p = 0; p < 8; p++) acc[p] = fmaf(f, w[p], acc[p]);
                }
                #pragma unroll
                for (int p = 0; p < 8; p++)
                    z_fu[(size_t)loc*64 + og8*8 + p] = f2b(fmaxf(acc[p], 0.f));
            }
        }
    }

    // ---- stats post-pass: L2-hot read-back, LDS combine, NSLOT atomics ----
    __syncthreads();        // z_fu stores drained; zt reads finished -> reuse
    {
        const int g3  = i & 7;           // 8 channel-groups of 8
        const int lr3 = i >> 3;
        float s[8], q2[8];
        #pragma unroll
        for (int k = 0; k < 8; k++) { s[k] = 0.f; q2[k] = 0.f; }
        #pragma unroll
        for (int li = 0; li < 4; li++) {
            const int l = lr3 + li*32;
            const uint4 v = *(const uint4*)(z_fu + (size_t)(loc_base + l)*64 + g3*8);
            unsigned int u[4] = { v.x, v.y, v.z, v.w };
            #pragma unroll
            for (int k = 0; k < 4; k++) {
                float f0 = b2f(u[k] & 0xffffu);
                float f1 = __uint_as_float(u[k] & 0xffff0000u);
                s[2*k]   += f0;  q2[2*k]   += f0*f0;
                s[2*k+1] += f1;  q2[2*k+1] += f1*f1;
            }
        }
        #pragma unroll
        for (int off = 8; off <= 32; off <<= 1) {
            #pragma unroll
            for (int k = 0; k < 8; k++) {
                s[k]  += __shfl_xor(s[k],  off);
                q2[k] += __shfl_xor(q2[k], off);
            }
        }
        float* red = (float*)zt;         // [4 wv][8 g][16] = 512 floats
        if (lane < 8) {                  // lane == g3 here
            #pragma unroll
            for (int k = 0; k < 8; k++) {
                red[(wv*8 + g3)*16 + k]     = s[k];
                red[(wv*8 + g3)*16 + 8 + k] = q2[k];
            }
        }
        __syncthreads();
        if (i < 128) {
            const int ch = i >> 1, which = i & 1;
            const int g = ch >> 3, k = ch & 7;
            const int idx = which*8 + k;
            float t0 = red[(0*8+g)*16 + idx] + red[(1*8+g)*16 + idx]
                     + red[(2*8+g)*16 + idx] + red[(3*8+g)*16 + idx];
            const int slot = blockIdx.x & (NSLOT-1);
            atomicAdd((which ? ssq_f : sum_f) + slot*64 + ch, t0);
        }
    }
}

// ---------------------------------------------------------------------------
// K5: finalize fu BN stats (NSLOT-slot sums)
// ---------------------------------------------------------------------------
__global__ void k_fin2(const float* __restrict__ sum_f, const float* __restrict__ ssq_f,
                       const float* __restrict__ fu_g,
                       float* __restrict__ mf, float* __restrict__ rfg) {
    int o = threadIdx.x;
    const float inv = 1.f / (float)N_;
    float sm = 0.f, sq = 0.f;
    for (int sl = 0; sl < NSLOT; sl++) { sm += sum_f[sl*64 + o]; sq += ssq_f[sl*64 + o]; }
    float m = sm*inv, v = sq*inv - m*m;
    mf[o] = m;
    rfg[o] = rsqrtf(v + 1e-5f) * fu_g[o];
}

// ---------------------------------------------------------------------------
// K6: apply fu BN, transpose [loc][64] -> out [b][o][j][t] f32. (unchanged)
// ---------------------------------------------------------------------------
__global__ __launch_bounds__(256) void k_out(const unsigned short* __restrict__ z_fu,
                                             const float* __restrict__ mf,
                                             const float* __restrict__ rfg,
                                             const float* __restrict__ fu_beta,
                                             float* __restrict__ out) {
    __shared__ __align__(16) unsigned short zt[256*66];
    const int i = threadIdx.x;
    const int bj = blockIdx.x;
    const int b = bj / J_, j = bj % J_;
    const int loc_base = bj * T_;

    for (int c = i; c < 2048; c += 256) {
        int row = c >> 3, k = c & 7;
        uint4 v = *(const uint4*)(z_fu + (size_t)(loc_base + row)*64 + k*8);
        unsigned int* dst = (unsigned int*)(zt + row*66 + k*8);
        dst[0] = v.x; dst[1] = v.y; dst[2] = v.z; dst[3] = v.w;
    }
    __syncthreads();

    const int t = i;
    const unsigned int* zrow = (const unsigned int*)zt + t*33;
    for (int o = 0; o < 64; o += 2) {
        unsigned int v = zrow[o >> 1];
        float f0 = b2f(v & 0xffffu);
        float f1 = __uint_as_float(v & 0xffff0000u);
        out[(((size_t)b*64 + o  )*J_ + j)*T_ + t] = (f0 - mf[o  ])*rfg[o  ] + fu_beta[o  ];
        out[(((size_t)b*64 + o+1)*J_ + j)*T_ + t] = (f1 - mf[o+1])*rfg[o+1] + fu_beta[o+1];
    }
}

// ---------------------------------------------------------------------------
extern "C" void kernel_launch(void* const* d_in, const int* in_sizes, int n_in,
                              void* d_out, int out_size, void* d_ws, size_t ws_size,
                              hipStream_t stream) {
    const float* x         = (const float*)d_in[0];
    const float* conv_w    = (const float*)d_in[1];
    const float* conv_b    = (const float*)d_in[2];
    const float* raw_gamma = (const float*)d_in[3];
    const float* raw_beta  = (const float*)d_in[4];
    const float* sp_W      = (const float*)d_in[5];
    const float* sp_b      = (const float*)d_in[6];
    const float* tp_W      = (const float*)d_in[7];
    const float* tp_b      = (const float*)d_in[8];
    const float* ps_w      = (const float*)d_in[9];
    const float* ps_b      = (const float*)d_in[10];
    const float* ps_gamma  = (const float*)d_in[11];
    const float* ps_beta   = (const float*)d_in[12];
    const float* fu_w      = (const float*)d_in[13];
    const float* fu_b      = (const float*)d_in[14];
    const float* fu_gamma  = (const float*)d_in[15];
    const float* fu_beta   = (const float*)d_in[16];
    const int*   neighbors = (const int*)d_in[17];

    char* ws = (char*)d_ws;
    unsigned short* zcat   = (unsigned short*)ws;                      // [N][128] bf16
    unsigned short* z_fu   = (unsigned short*)(ws + 104857600);        // [N][64] bf16
    // partial/red2 OVERLAY the z_fu region: written by k_sig/k_red1 and fully
    // consumed (k_red1/k_fin1) before k_fu writes z_fu — stream-ordered.
    float* partial = (float*)(ws + 104857600);                 // [6400][256] 6.55MB
    float* red2    = (float*)(ws + 104857600 + 6553600);       // [NRED][256] 64KB
    size_t off = 157286400;
    float* wsig_t = (float*)(ws + off);          off += 168*64*4;      // [168][64] f32
    float* w12s_t = (float*)(ws + off);          off += 128*64*4;      // [128][64] f32
    unsigned short* w12h = (unsigned short*)(ws + off); off += 64*WST*2;
    unsigned short* w12l = (unsigned short*)(ws + off); off += 64*WST*2;
    float* f32s   = (float*)(ws + off);
    float* cb     = f32s;                         // 64
    float* fb2    = f32s + 64;                    // 64
    float* mf     = f32s + 128;                   // 64
    float* rfg    = f32s + 192;                   // 64
    float* sum_f  = f32s + 256;                   // NSLOT*64
    float* ssq_f  = sum_f + NSLOT*64;             // NSLOT*64

    hipMemsetAsync(sum_f, 0, (size_t)NSLOT*128*sizeof(float), stream);

    k_prep<<<169, 64, 0, stream>>>(sp_W, sp_b, tp_W, tp_b, ps_w, ps_b, wsig_t, cb);
    k_sig<<<6400, 256, 0, stream>>>(x, neighbors, wsig_t, cb, conv_w, conv_b, zcat,
                                    partial);
    k_red1<<<NRED, 256, 0, stream>>>(partial, red2);
    k_fin1<<<1, 64, 0, stream>>>(red2, raw_gamma, raw_beta,
                                 ps_gamma, ps_beta, fu_w, fu_b,
                                 w12h, w12l, w12s_t, fb2);
    k_fu<<<3200, 256, 0, stream>>>(zcat, w12h, w12l, w12s_t, fb2, z_fu,
                                   sum_f, ssq_f);
    k_fin2<<<1, 64, 0, stream>>>(sum_f, ssq_f, fu_gamma, mf, rfg);
    k_out<<<1600, 256, 0, stream>>>(z_fu, mf, rfg, fu_beta, (float*)d_out);
}

// Round 9
// 413.700 us; speedup vs baseline: 2.8003x; 1.1147x over previous
//
#include <hip/hip_runtime.h>
#include <hip/hip_bf16.h>
#include <stdint.h>

#define B_   64
#define C_   3
#define J_   25
#define T_   256
#define CO_  64
#define N_   (B_*J_*T_)     // 409600 locations, loc = (b*J_+j)*T_ + t
#define SIGD 84
#define FSTR 177            // feats LDS stride (f32) — (17*lt+k)%32: 2-way banks only
#define WST  136            // w12 bf16 row stride (elements), K=128 + 8 pad
#define NSLOT 32            // f-stat slots (k_fu post-pass, verified r7/r8)

typedef short   s16x8  __attribute__((ext_vector_type(8)));
typedef __bf16  bf16x8 __attribute__((ext_vector_type(8)));
typedef float   f32x4  __attribute__((ext_vector_type(4)));
typedef float   f32x2  __attribute__((ext_vector_type(2)));

__device__ __forceinline__ unsigned short f2b(float f) {
    unsigned int u = __float_as_uint(f);
    u += 0x7fffu + ((u >> 16) & 1u);          // round-to-nearest-even
    return (unsigned short)(u >> 16);
}
__device__ __forceinline__ float b2f(unsigned int bits_lo16) {
    return __uint_as_float(bits_lo16 << 16);
}
__device__ __forceinline__ unsigned int pack2(float a, float b) {
    return (unsigned int)f2b(a) | ((unsigned int)f2b(b) << 16);
}
__device__ __forceinline__ void split2(float f, unsigned short& h, unsigned short& l) {
    h = f2b(f);
    l = f2b(f - b2f((unsigned int)h));
}

// ---------------------------------------------------------------------------
// depth-3 signature of a 3-increment path in 4 dims (verified).
// ---------------------------------------------------------------------------
__device__ __forceinline__ void sig3(const float v0[4], const float v1[4],
                                     const float v2[4], float* __restrict__ S) {
    float* S1 = S;
    float* S2 = S + 4;
    float* S3 = S + 20;
    #pragma unroll
    for (int i = 0; i < 4; i++) S1[i] = v0[i];
    #pragma unroll
    for (int i = 0; i < 4; i++)
        #pragma unroll
        for (int j = 0; j < 4; j++) S2[i*4+j] = 0.5f * v0[i] * v0[j];
    #pragma unroll
    for (int i = 0; i < 4; i++)
        #pragma unroll
        for (int j = 0; j < 4; j++)
            #pragma unroll
            for (int k = 0; k < 4; k++)
                S3[i*16+j*4+k] = S2[i*4+j] * v0[k] * (1.f/3.f);

    #pragma unroll
    for (int s = 0; s < 2; s++) {
        const float* v = (s == 0) ? v1 : v2;
        float B2[16], v3[4];
        #pragma unroll
        for (int k = 0; k < 4; k++) v3[k] = v[k] * (1.f/3.f);
        #pragma unroll
        for (int i = 0; i < 4; i++)
            #pragma unroll
            for (int j = 0; j < 4; j++) B2[i*4+j] = 0.5f * v[i] * v[j];
        #pragma unroll
        for (int i = 0; i < 4; i++)
            #pragma unroll
            for (int j = 0; j < 4; j++)
                #pragma unroll
                for (int k = 0; k < 4; k++)
                    S3[i*16+j*4+k] += B2[i*4+j]*v3[k] + S1[i]*B2[j*4+k] + S2[i*4+j]*v[k];
        #pragma unroll
        for (int i = 0; i < 4; i++)
            #pragma unroll
            for (int j = 0; j < 4; j++) S2[i*4+j] += B2[i*4+j] + S1[i]*v[j];
        #pragma unroll
        for (int i = 0; i < 4; i++) S1[i] += v[i];
    }
}

// ---------------------------------------------------------------------------
// K0: fold signet weights through ps_w into f32 wsig_t[168][64] (k-major).
// grid=169 (k; 168=bias), block=64 (o).   (verified baseline)
// ---------------------------------------------------------------------------
__global__ void k_prep(const float* __restrict__ sp_W, const float* __restrict__ sp_b,
                       const float* __restrict__ tp_W, const float* __restrict__ tp_b,
                       const float* __restrict__ ps_w, const float* __restrict__ ps_b,
                       float* __restrict__ wsig_t, float* __restrict__ cb) {
    int k = blockIdx.x;
    int o = threadIdx.x;
    if (k < SIGD) {
        float v = 0.f;
        for (int i = 0; i < 64; i++) v += sp_W[k*64+i] * ps_w[o*128+i];
        wsig_t[k*64 + o] = v;
    } else if (k < 2*SIGD) {
        int m = k - SIGD;
        float v = 0.f;
        for (int i = 0; i < 64; i++) v += tp_W[m*64+i] * ps_w[o*128+64+i];
        wsig_t[k*64 + o] = v;
    } else {
        float a = ps_b[o];
        for (int i = 0; i < 64; i++)
            a += ps_w[o*128+i]*sp_b[i] + ps_w[o*128+64+i]*tp_b[i];
        cb[o] = a;
    }
}

// ---------------------------------------------------------------------------
// K1: fused conv1x3 + signatures + packed-f32 folded matvec.
// BYTE-IDENTICAL to the 436us baseline k_sig (verified r0).  r8's in-kernel
// stats butterflies cost +58us (LDS-pipe shfl chains on the critical path)
// vs the ~20us separate stats kernel — reverted.
// Grid: 1600 (b,j) x 4 quarters, 64 locs/block.
// ---------------------------------------------------------------------------
__global__ __launch_bounds__(256) void k_sig(const float* __restrict__ x,
                                             const int* __restrict__ nbr,
                                             const float* __restrict__ wsig_t,
                                             const float* __restrict__ cb,
                                             const float* __restrict__ conv_w,
                                             const float* __restrict__ conv_b,
                                             unsigned short* __restrict__ zcat) {
    __shared__ float feats[64*FSTR];   // 45312 B

    const int i       = threadIdx.x;
    const int quarter = blockIdx.x & 3;
    const int bj      = blockIdx.x >> 2;
    const int b       = bj / J_, j = bj % J_;
    const int loc_base = bj*T_ + quarter*64;

    if (i < 128) {
        const int lt   = i >> 1;
        const int path = i & 1;
        const int t    = quarter*64 + lt;
        float p0[4], p1[4], p2[4];
        p0[0] = 0.f; p1[0] = 0.5f; p2[0] = 1.0f;
        if (path == 0) {
            int n0 = nbr[j*3+0], n1 = nbr[j*3+1], n2 = nbr[j*3+2];
            #pragma unroll
            for (int c = 0; c < 3; c++) {
                const float* xc = x + ((size_t)(b*3+c)*J_)*T_ + t;
                p0[c+1] = xc[n0*T_];
                p1[c+1] = xc[n1*T_];
                p2[c+1] = xc[n2*T_];
            }
        } else {
            int tm = (t > 0)    ? t-1 : 0;
            int tp = (t < T_-1) ? t+1 : T_-1;
            #pragma unroll
            for (int c = 0; c < 3; c++) {
                const float* xr = x + ((size_t)(b*3+c)*J_ + j)*T_;
                p0[c+1] = xr[tm];
                p1[c+1] = xr[t];
                p2[c+1] = xr[tp];
            }
        }
        float v0[4], v1[4], v2[4];
        #pragma unroll
        for (int d = 0; d < 4; d++) { v0[d]=p0[d]; v1[d]=p1[d]-p0[d]; v2[d]=p2[d]-p1[d]; }
        float S[SIGD];
        sig3(v0, v1, v2, S);
        float* frow = feats + lt*FSTR + path*SIGD;
        #pragma unroll
        for (int m = 0; m < SIGD; m++) frow[m] = S[m];
    } else {
        const int ci  = i - 128;
        const int lt  = ci >> 1;
        const int chh = ci & 1;
        const int t   = quarter*64 + lt;
        const int loc = loc_base + lt;
        float xm[3], x0[3], xp[3];
        #pragma unroll
        for (int c = 0; c < 3; c++) {
            const float* xr = x + ((size_t)(b*3+c)*J_ + j)*T_;
            xm[c] = (t > 0)     ? xr[t-1] : 0.f;
            x0[c] = xr[t];
            xp[c] = (t < T_-1)  ? xr[t+1] : 0.f;
        }
        unsigned int packed[16];
        #pragma unroll
        for (int oo2 = 0; oo2 < 16; oo2++) {
            float r[2];
            #pragma unroll
            for (int e = 0; e < 2; e++) {
                int o = chh*32 + oo2*2 + e;
                float acc = conv_b[o];
                #pragma unroll
                for (int c = 0; c < 3; c++) {
                    const float* wr = conv_w + (o*3+c)*3;
                    acc += wr[0]*xm[c] + wr[1]*x0[c] + wr[2]*xp[c];
                }
                r[e] = fmaxf(acc, 0.f);
            }
            packed[oo2] = pack2(r[0], r[1]);
        }
        uint4* dst = (uint4*)(zcat + (size_t)loc*128 + chh*32);
        #pragma unroll
        for (int k = 0; k < 4; k++)
            dst[k] = make_uint4(packed[k*4+0], packed[k*4+1], packed[k*4+2], packed[k*4+3]);
    }
    __syncthreads();

    // ---- packed matvec: z_ps[loc][o] = relu(sum_k w[k][o]*f[loc][k]+cb) ----
    const int og = __builtin_amdgcn_readfirstlane(i >> 6);   // wave-uniform o-tile
    const int lt = i & 63;
    const int loc = loc_base + lt;
    const float* wt = wsig_t + og*16;        // + k*64
    f32x2 acc2[8];
    {
        const f32x2* cbp = (const f32x2*)(cb + og*16);
        #pragma unroll
        for (int p = 0; p < 8; p++) acc2[p] = cbp[p];
    }
    const float* frow = feats + lt*FSTR;
    #pragma unroll 4
    for (int k = 0; k < 2*SIGD; k++) {
        float f = frow[k];
        f32x2 f2 = { f, f };
        const f32x2* w2 = (const f32x2*)(wt + k*64);
        #pragma unroll
        for (int p = 0; p < 8; p++) acc2[p] += f2 * w2[p];   // v_pk_fma_f32
    }
    unsigned int pk[8];
    #pragma unroll
    for (int p = 0; p < 8; p++)
        pk[p] = pack2(fmaxf(acc2[p][0],0.f), fmaxf(acc2[p][1],0.f));
    uint4* dst = (uint4*)(zcat + (size_t)loc*128 + 64 + og*16);
    dst[0] = make_uint4(pk[0], pk[1], pk[2], pk[3]);
    dst[1] = make_uint4(pk[4], pk[5], pk[6], pk[7]);
}

// ---------------------------------------------------------------------------
// per-channel sum/ssq over [N_][128] bf16 (verified baseline r0).
// ---------------------------------------------------------------------------
template<int NCH>
__global__ __launch_bounds__(256) void k_stats(const unsigned short* __restrict__ z,
                                               float* __restrict__ sum,
                                               float* __restrict__ ssq) {
    constexpr int G  = NCH/8;
    constexpr int LP = 256/G;
    const int i = threadIdx.x;
    const int g = i % G;
    const int lr = i / G;
    const int base = blockIdx.x * 1600;
    float s[8], qq[8];
    #pragma unroll
    for (int k = 0; k < 8; k++) { s[k] = 0.f; qq[k] = 0.f; }
    for (int l = lr; l < 1600; l += LP) {
        const uint4 v = *(const uint4*)(z + (size_t)(base + l)*NCH + g*8);
        unsigned int u[4] = { v.x, v.y, v.z, v.w };
        #pragma unroll
        for (int k = 0; k < 4; k++) {
            float f0 = b2f(u[k] & 0xffffu);
            float f1 = __uint_as_float(u[k] & 0xffff0000u);
            s[2*k]   += f0;  qq[2*k]   += f0*f0;
            s[2*k+1] += f1;  qq[2*k+1] += f1*f1;
        }
    }
    const int lane = i & 63, wv = i >> 6;
    for (int off = 32; off >= G; off >>= 1) {
        #pragma unroll
        for (int k = 0; k < 8; k++) {
            s[k]  += __shfl_down(s[k],  off);
            qq[k] += __shfl_down(qq[k], off);
        }
    }
    __shared__ float red[4][G][16];
    if (lane < G) {
        #pragma unroll
        for (int k = 0; k < 8; k++) { red[wv][lane][k] = s[k]; red[wv][lane][8+k] = qq[k]; }
    }
    __syncthreads();
    if (i < G*16) {
        int g2 = i >> 4, slot = i & 15;
        float v = red[0][g2][slot] + red[1][g2][slot] + red[2][g2][slot] + red[3][g2][slot];
        int ch = g2*8 + (slot & 7);
        atomicAdd((slot < 8 ? sum : ssq) + ch, v);
    }
}

// ---------------------------------------------------------------------------
// K3: finalize conv/ps BN; fold into fu weights. (verified baseline r0)
// ---------------------------------------------------------------------------
__global__ void k_fin1(const float* __restrict__ sum_cp, const float* __restrict__ ssq_cp,
                       const float* __restrict__ raw_g, const float* __restrict__ raw_b,
                       const float* __restrict__ ps_g,  const float* __restrict__ ps_bt,
                       const float* __restrict__ fu_w,  const float* __restrict__ fu_b,
                       unsigned short* __restrict__ w12h, unsigned short* __restrict__ w12l,
                       float* __restrict__ w12s_t, float* __restrict__ fb2) {
    __shared__ float a[128], d[128];
    int i = threadIdx.x;    // 64
    const float inv = 1.f / (float)N_;
    {
        float m = sum_cp[i]*inv, v = ssq_cp[i]*inv - m*m;
        float sc = rsqrtf(v + 1e-5f) * raw_g[i];
        a[i] = sc; d[i] = raw_b[i] - m*sc;
    }
    {
        float m = sum_cp[64+i]*inv, v = ssq_cp[64+i]*inv - m*m;
        float sc = rsqrtf(v + 1e-5f) * ps_g[i];
        a[64+i] = sc; d[64+i] = ps_bt[i] - m*sc;
    }
    __syncthreads();
    int o = i;
    float fb = fu_b[o];
    for (int k = 0; k < 128; k++) {
        float w = fu_w[o*128 + k];
        fb += w * d[k];
        float ws = w * a[k];
        w12s_t[k*64 + o] = ws;
        unsigned short h, l;
        split2(ws, h, l);
        w12h[o*WST + k] = h;
        w12l[o*WST + k] = l;
    }
    for (int k = 128; k < WST; k++) { w12h[o*WST + k] = 0; w12l[o*WST + k] = 0; }
    fb2[o] = fb;
}

// ---------------------------------------------------------------------------
// K4: fu GEMM via MFMA with in-kernel C/D-orientation probe + fused z_fu
// stats post-pass (LDS combine + NSLOT atomics).  Verified r7 AND r8.
// ---------------------------------------------------------------------------
__global__ __launch_bounds__(256) void k_fu(const unsigned short* __restrict__ zcat,
                                            const unsigned short* __restrict__ w12h,
                                            const unsigned short* __restrict__ w12l,
                                            const float* __restrict__ w12s_t,
                                            const float* __restrict__ fb2,
                                            unsigned short* __restrict__ z_fu,
                                            float* __restrict__ sum_f,
                                            float* __restrict__ ssq_f) {
    __shared__ __align__(16) unsigned short zt[128*WST];   // 34816 B
    const int i = threadIdx.x;
    const int loc_base = blockIdx.x * 128;

    for (int c = i; c < 2048; c += 256) {
        int row = c >> 4, k = c & 15;
        s16x8 v = *(const s16x8*)(zcat + (size_t)(loc_base + row)*128 + k*8);
        *(s16x8*)(zt + row*WST + k*8) = v;
    }
    __syncthreads();

    const int lane = i & 63, wv = i >> 6;
    const int mrow = lane & 15, q = lane >> 4;
    const f32x4 zero = {0.f, 0.f, 0.f, 0.f};

    // ---- layout probe ----
    bf16x8 ap, bp;
    #pragma unroll
    for (int jj = 0; jj < 8; jj++) { ap[jj] = (__bf16)(float)mrow; bp[jj] = (__bf16)1.0f; }
    f32x4 pv = __builtin_amdgcn_mfma_f32_16x16x32_bf16(ap, bp, zero, 0, 0, 0);
    bool cC = true, cT = true;
    #pragma unroll
    for (int r = 0; r < 4; r++) {
        cC = cC && (pv[r] == 32.f*(float)(q*4 + r));
        cT = cT && (pv[r] == 32.f*(float)mrow);
    }
    const bool okC = (__ballot(cC) == ~0ull);
    const bool okT = (!okC) && (__ballot(cT) == ~0ull);

    if (okC || okT) {
        bf16x8 ah[4], al[4];
        {
            const unsigned short* arh = w12h + (size_t)(wv*16 + mrow)*WST + q*8;
            const unsigned short* arl = w12l + (size_t)(wv*16 + mrow)*WST + q*8;
            #pragma unroll
            for (int s = 0; s < 4; s++) {
                ah[s] = __builtin_bit_cast(bf16x8, *(const s16x8*)(arh + s*32));
                al[s] = __builtin_bit_cast(bf16x8, *(const s16x8*)(arl + s*32));
            }
        }
        f32x4 accs[8];
        #pragma unroll
        for (int lt8 = 0; lt8 < 8; lt8++) {
            const unsigned short* brow = zt + (size_t)(lt8*16 + mrow)*WST + q*8;
            f32x4 acc = zero;
            #pragma unroll
            for (int s = 0; s < 4; s++) {
                bf16x8 bfrag = __builtin_bit_cast(bf16x8, *(const s16x8*)(brow + s*32));
                acc = __builtin_amdgcn_mfma_f32_16x16x32_bf16(ah[s], bfrag, acc, 0, 0, 0);
                acc = __builtin_amdgcn_mfma_f32_16x16x32_bf16(al[s], bfrag, acc, 0, 0, 0);
            }
            accs[lt8] = acc;
        }
        __syncthreads();

        unsigned short* ot = zt;       // alias as [128 loc][72 o]
        if (okC) {
            const float4 fbv = *(const float4*)(fb2 + wv*16 + q*4);
            #pragma unroll
            for (int lt8 = 0; lt8 < 8; lt8++) {
                int row = lt8*16 + mrow;
                int o   = wv*16 + q*4;
                uint2 w;
                w.x = pack2(fmaxf(accs[lt8][0]+fbv.x,0.f), fmaxf(accs[lt8][1]+fbv.y,0.f));
                w.y = pack2(fmaxf(accs[lt8][2]+fbv.z,0.f), fmaxf(accs[lt8][3]+fbv.w,0.f));
                *(uint2*)(ot + row*72 + o) = w;
            }
        } else {
            const float fb1 = fb2[wv*16 + mrow];
            #pragma unroll
            for (int lt8 = 0; lt8 < 8; lt8++) {
                #pragma unroll
                for (int r = 0; r < 4; r++) {
                    int row = lt8*16 + q*4 + r;
                    ot[row*72 + wv*16 + mrow] = f2b(fmaxf(accs[lt8][r]+fb1, 0.f));
                }
            }
        }
        __syncthreads();
        for (int c = i; c < 1024; c += 256) {
            int row = c >> 3, k = c & 7;
            s16x8 v = *(const s16x8*)(ot + row*72 + k*8);
            *(s16x8*)(z_fu + (size_t)(loc_base + row)*64 + k*8) = v;
        }
    } else {
        // ---- scalar fallback (correctness net; slow but exact) ----
        if (i < 128) {
            const unsigned short* fr = zt + i*WST;
            const int loc = loc_base + i;
            for (int og8 = 0; og8 < 8; og8++) {
                float acc[8];
                #pragma unroll
                for (int p = 0; p < 8; p++) acc[p] = fb2[og8*8 + p];
                for (int k = 0; k < 128; k++) {
                    float f = b2f(fr[k]);
                    const float* w = w12s_t + k*64 + og8*8;
                    #pragma unroll
                    for (int p = 0; p < 8; p++) acc[p] = fmaf(f, w[p], acc[p]);
                }
                #pragma unroll
                for (int p = 0; p < 8; p++)
                    z_fu[(size_t)loc*64 + og8*8 + p] = f2b(fmaxf(acc[p], 0.f));
            }
        }
    }

    // ---- stats post-pass: L2-hot read-back, LDS combine, NSLOT atomics ----
    __syncthreads();        // z_fu stores drained; zt reads finished -> reuse
    {
        const int g3  = i & 7;           // 8 channel-groups of 8
        const int lr3 = i >> 3;
        float s[8], q2[8];
        #pragma unroll
        for (int k = 0; k < 8; k++) { s[k] = 0.f; q2[k] = 0.f; }
        #pragma unroll
        for (int li = 0; li < 4; li++) {
            const int l = lr3 + li*32;
            const uint4 v = *(const uint4*)(z_fu + (size_t)(loc_base + l)*64 + g3*8);
            unsigned int u[4] = { v.x, v.y, v.z, v.w };
            #pragma unroll
            for (int k = 0; k < 4; k++) {
                float f0 = b2f(u[k] & 0xffffu);
                float f1 = __uint_as_float(u[k] & 0xffff0000u);
                s[2*k]   += f0;  q2[2*k]   += f0*f0;
                s[2*k+1] += f1;  q2[2*k+1] += f1*f1;
            }
        }
        #pragma unroll
        for (int off = 8; off <= 32; off <<= 1) {
            #pragma unroll
            for (int k = 0; k < 8; k++) {
                s[k]  += __shfl_xor(s[k],  off);
                q2[k] += __shfl_xor(q2[k], off);
            }
        }
        float* red = (float*)zt;         // [4 wv][8 g][16] = 512 floats
        if (lane < 8) {                  // lane == g3 here
            #pragma unroll
            for (int k = 0; k < 8; k++) {
                red[(wv*8 + g3)*16 + k]     = s[k];
                red[(wv*8 + g3)*16 + 8 + k] = q2[k];
            }
        }
        __syncthreads();
        if (i < 128) {
            const int ch = i >> 1, which = i & 1;
            const int g = ch >> 3, k = ch & 7;
            const int idx = which*8 + k;
            float t0 = red[(0*8+g)*16 + idx] + red[(1*8+g)*16 + idx]
                     + red[(2*8+g)*16 + idx] + red[(3*8+g)*16 + idx];
            const int slot = blockIdx.x & (NSLOT-1);
            atomicAdd((which ? ssq_f : sum_f) + slot*64 + ch, t0);
        }
    }
}

// ---------------------------------------------------------------------------
// K5: finalize fu BN stats (NSLOT-slot sums) — verified r7/r8
// ---------------------------------------------------------------------------
__global__ void k_fin2(const float* __restrict__ sum_f, const float* __restrict__ ssq_f,
                       const float* __restrict__ fu_g,
                       float* __restrict__ mf, float* __restrict__ rfg) {
    int o = threadIdx.x;
    const float inv = 1.f / (float)N_;
    float sm = 0.f, sq = 0.f;
    for (int sl = 0; sl < NSLOT; sl++) { sm += sum_f[sl*64 + o]; sq += ssq_f[sl*64 + o]; }
    float m = sm*inv, v = sq*inv - m*m;
    mf[o] = m;
    rfg[o] = rsqrtf(v + 1e-5f) * fu_g[o];
}

// ---------------------------------------------------------------------------
// K6: apply fu BN, transpose [loc][64] -> out [b][o][j][t] f32. (verified r0)
// ---------------------------------------------------------------------------
__global__ __launch_bounds__(256) void k_out(const unsigned short* __restrict__ z_fu,
                                             const float* __restrict__ mf,
                                             const float* __restrict__ rfg,
                                             const float* __restrict__ fu_beta,
                                             float* __restrict__ out) {
    __shared__ __align__(16) unsigned short zt[256*66];
    const int i = threadIdx.x;
    const int bj = blockIdx.x;
    const int b = bj / J_, j = bj % J_;
    const int loc_base = bj * T_;

    for (int c = i; c < 2048; c += 256) {
        int row = c >> 3, k = c & 7;
        uint4 v = *(const uint4*)(z_fu + (size_t)(loc_base + row)*64 + k*8);
        unsigned int* dst = (unsigned int*)(zt + row*66 + k*8);
        dst[0] = v.x; dst[1] = v.y; dst[2] = v.z; dst[3] = v.w;
    }
    __syncthreads();

    const int t = i;
    const unsigned int* zrow = (const unsigned int*)zt + t*33;
    for (int o = 0; o < 64; o += 2) {
        unsigned int v = zrow[o >> 1];
        float f0 = b2f(v & 0xffffu);
        float f1 = __uint_as_float(v & 0xffff0000u);
        out[(((size_t)b*64 + o  )*J_ + j)*T_ + t] = (f0 - mf[o  ])*rfg[o  ] + fu_beta[o  ];
        out[(((size_t)b*64 + o+1)*J_ + j)*T_ + t] = (f1 - mf[o+1])*rfg[o+1] + fu_beta[o+1];
    }
}

// ---------------------------------------------------------------------------
extern "C" void kernel_launch(void* const* d_in, const int* in_sizes, int n_in,
                              void* d_out, int out_size, void* d_ws, size_t ws_size,
                              hipStream_t stream) {
    const float* x         = (const float*)d_in[0];
    const float* conv_w    = (const float*)d_in[1];
    const float* conv_b    = (const float*)d_in[2];
    const float* raw_gamma = (const float*)d_in[3];
    const float* raw_beta  = (const float*)d_in[4];
    const float* sp_W      = (const float*)d_in[5];
    const float* sp_b      = (const float*)d_in[6];
    const float* tp_W      = (const float*)d_in[7];
    const float* tp_b      = (const float*)d_in[8];
    const float* ps_w      = (const float*)d_in[9];
    const float* ps_b      = (const float*)d_in[10];
    const float* ps_gamma  = (const float*)d_in[11];
    const float* ps_beta   = (const float*)d_in[12];
    const float* fu_w      = (const float*)d_in[13];
    const float* fu_b      = (const float*)d_in[14];
    const float* fu_gamma  = (const float*)d_in[15];
    const float* fu_beta   = (const float*)d_in[16];
    const int*   neighbors = (const int*)d_in[17];

    char* ws = (char*)d_ws;
    unsigned short* zcat   = (unsigned short*)ws;                      // [N][128] bf16
    unsigned short* z_fu   = (unsigned short*)(ws + 104857600);        // [N][64] bf16
    size_t off = 157286400;
    float* wsig_t = (float*)(ws + off);          off += 168*64*4;      // [168][64] f32
    float* w12s_t = (float*)(ws + off);          off += 128*64*4;      // [128][64] f32
    unsigned short* w12h = (unsigned short*)(ws + off); off += 64*WST*2;
    unsigned short* w12l = (unsigned short*)(ws + off); off += 64*WST*2;
    float* f32s   = (float*)(ws + off);
    float* cb     = f32s;                         // 64
    float* fb2    = f32s + 64;                    // 64
    float* mf     = f32s + 128;                   // 64
    float* rfg    = f32s + 192;                   // 64
    float* sum_cp = f32s + 256;                   // 128
    float* ssq_cp = f32s + 384;                   // 128
    float* sum_f  = f32s + 512;                   // NSLOT*64
    float* ssq_f  = sum_f + NSLOT*64;             // NSLOT*64

    hipMemsetAsync(sum_cp, 0, (size_t)(256 + NSLOT*128)*sizeof(float), stream);

    k_prep<<<169, 64, 0, stream>>>(sp_W, sp_b, tp_W, tp_b, ps_w, ps_b, wsig_t, cb);
    k_sig<<<6400, 256, 0, stream>>>(x, neighbors, wsig_t, cb, conv_w, conv_b, zcat);
    k_stats<128><<<256, 256, 0, stream>>>(zcat, sum_cp, ssq_cp);
    k_fin1<<<1, 64, 0, stream>>>(sum_cp, ssq_cp, raw_gamma, raw_beta,
                                 ps_gamma, ps_beta, fu_w, fu_b,
                                 w12h, w12l, w12s_t, fb2);
    k_fu<<<3200, 256, 0, stream>>>(zcat, w12h, w12l, w12s_t, fb2, z_fu,
                                   sum_f, ssq_f);
    k_fin2<<<1, 64, 0, stream>>>(sum_f, ssq_f, fu_gamma, mf, rfg);
    k_out<<<1600, 256, 0, stream>>>(z_fu, mf, rfg, fu_beta, (float*)d_out);
}

// Round 10
// 413.514 us; speedup vs baseline: 2.8015x; 1.0004x over previous
//
#include <hip/hip_runtime.h>
#include <hip/hip_bf16.h>
#include <stdint.h>

#define B_   64
#define C_   3
#define J_   25
#define T_   256
#define CO_  64
#define N_   (B_*J_*T_)     // 409600 locations, loc = (b*J_+j)*T_ + t
#define SIGD 84
#define FSTR 177            // feats LDS stride (f32) — (17*lt+k)%32: 2-way banks only
#define WST  136            // w12 bf16 row stride (elements), K=128 + 8 pad
#define NSLOT 32            // f-stat slots (verified r7/r8/r9)

typedef short   s16x8  __attribute__((ext_vector_type(8)));
typedef __bf16  bf16x8 __attribute__((ext_vector_type(8)));
typedef float   f32x4  __attribute__((ext_vector_type(4)));
typedef float   f32x2  __attribute__((ext_vector_type(2)));

__device__ __forceinline__ unsigned short f2b(float f) {
    unsigned int u = __float_as_uint(f);
    u += 0x7fffu + ((u >> 16) & 1u);          // round-to-nearest-even
    return (unsigned short)(u >> 16);
}
__device__ __forceinline__ float b2f(unsigned int bits_lo16) {
    return __uint_as_float(bits_lo16 << 16);
}
__device__ __forceinline__ unsigned int pack2(float a, float b) {
    return (unsigned int)f2b(a) | ((unsigned int)f2b(b) << 16);
}
__device__ __forceinline__ void split2(float f, unsigned short& h, unsigned short& l) {
    h = f2b(f);
    l = f2b(f - b2f((unsigned int)h));
}

// ---------------------------------------------------------------------------
// depth-3 signature of a 3-increment path in 4 dims (verified).
// ---------------------------------------------------------------------------
__device__ __forceinline__ void sig3(const float v0[4], const float v1[4],
                                     const float v2[4], float* __restrict__ S) {
    float* S1 = S;
    float* S2 = S + 4;
    float* S3 = S + 20;
    #pragma unroll
    for (int i = 0; i < 4; i++) S1[i] = v0[i];
    #pragma unroll
    for (int i = 0; i < 4; i++)
        #pragma unroll
        for (int j = 0; j < 4; j++) S2[i*4+j] = 0.5f * v0[i] * v0[j];
    #pragma unroll
    for (int i = 0; i < 4; i++)
        #pragma unroll
        for (int j = 0; j < 4; j++)
            #pragma unroll
            for (int k = 0; k < 4; k++)
                S3[i*16+j*4+k] = S2[i*4+j] * v0[k] * (1.f/3.f);

    #pragma unroll
    for (int s = 0; s < 2; s++) {
        const float* v = (s == 0) ? v1 : v2;
        float B2[16], v3[4];
        #pragma unroll
        for (int k = 0; k < 4; k++) v3[k] = v[k] * (1.f/3.f);
        #pragma unroll
        for (int i = 0; i < 4; i++)
            #pragma unroll
            for (int j = 0; j < 4; j++) B2[i*4+j] = 0.5f * v[i] * v[j];
        #pragma unroll
        for (int i = 0; i < 4; i++)
            #pragma unroll
            for (int j = 0; j < 4; j++)
                #pragma unroll
                for (int k = 0; k < 4; k++)
                    S3[i*16+j*4+k] += B2[i*4+j]*v3[k] + S1[i]*B2[j*4+k] + S2[i*4+j]*v[k];
        #pragma unroll
        for (int i = 0; i < 4; i++)
            #pragma unroll
            for (int j = 0; j < 4; j++) S2[i*4+j] += B2[i*4+j] + S1[i]*v[j];
        #pragma unroll
        for (int i = 0; i < 4; i++) S1[i] += v[i];
    }
}

// ---------------------------------------------------------------------------
// K0: fold signet weights through ps_w into f32 wsig_t[168][64] (k-major).
// grid=169 (k; 168=bias), block=64 (o).   (verified baseline)
// ---------------------------------------------------------------------------
__global__ void k_prep(const float* __restrict__ sp_W, const float* __restrict__ sp_b,
                       const float* __restrict__ tp_W, const float* __restrict__ tp_b,
                       const float* __restrict__ ps_w, const float* __restrict__ ps_b,
                       float* __restrict__ wsig_t, float* __restrict__ cb) {
    int k = blockIdx.x;
    int o = threadIdx.x;
    if (k < SIGD) {
        float v = 0.f;
        for (int i = 0; i < 64; i++) v += sp_W[k*64+i] * ps_w[o*128+i];
        wsig_t[k*64 + o] = v;
    } else if (k < 2*SIGD) {
        int m = k - SIGD;
        float v = 0.f;
        for (int i = 0; i < 64; i++) v += tp_W[m*64+i] * ps_w[o*128+64+i];
        wsig_t[k*64 + o] = v;
    } else {
        float a = ps_b[o];
        for (int i = 0; i < 64; i++)
            a += ps_w[o*128+i]*sp_b[i] + ps_w[o*128+64+i]*tp_b[i];
        cb[o] = a;
    }
}

// ---------------------------------------------------------------------------
// K1: fused conv1x3 + signatures + packed-f32 folded matvec (verified r0/r9;
// only change: matvec unroll 4->8 for deeper LDS-load latency cover).
// Grid: 1600 (b,j) x 4 quarters, 64 locs/block.
// ---------------------------------------------------------------------------
__global__ __launch_bounds__(256) void k_sig(const float* __restrict__ x,
                                             const int* __restrict__ nbr,
                                             const float* __restrict__ wsig_t,
                                             const float* __restrict__ cb,
                                             const float* __restrict__ conv_w,
                                             const float* __restrict__ conv_b,
                                             unsigned short* __restrict__ zcat) {
    __shared__ float feats[64*FSTR];   // 45312 B

    const int i       = threadIdx.x;
    const int quarter = blockIdx.x & 3;
    const int bj      = blockIdx.x >> 2;
    const int b       = bj / J_, j = bj % J_;
    const int loc_base = bj*T_ + quarter*64;

    if (i < 128) {
        const int lt   = i >> 1;
        const int path = i & 1;
        const int t    = quarter*64 + lt;
        float p0[4], p1[4], p2[4];
        p0[0] = 0.f; p1[0] = 0.5f; p2[0] = 1.0f;
        if (path == 0) {
            int n0 = nbr[j*3+0], n1 = nbr[j*3+1], n2 = nbr[j*3+2];
            #pragma unroll
            for (int c = 0; c < 3; c++) {
                const float* xc = x + ((size_t)(b*3+c)*J_)*T_ + t;
                p0[c+1] = xc[n0*T_];
                p1[c+1] = xc[n1*T_];
                p2[c+1] = xc[n2*T_];
            }
        } else {
            int tm = (t > 0)    ? t-1 : 0;
            int tp = (t < T_-1) ? t+1 : T_-1;
            #pragma unroll
            for (int c = 0; c < 3; c++) {
                const float* xr = x + ((size_t)(b*3+c)*J_ + j)*T_;
                p0[c+1] = xr[tm];
                p1[c+1] = xr[t];
                p2[c+1] = xr[tp];
            }
        }
        float v0[4], v1[4], v2[4];
        #pragma unroll
        for (int d = 0; d < 4; d++) { v0[d]=p0[d]; v1[d]=p1[d]-p0[d]; v2[d]=p2[d]-p1[d]; }
        float S[SIGD];
        sig3(v0, v1, v2, S);
        float* frow = feats + lt*FSTR + path*SIGD;
        #pragma unroll
        for (int m = 0; m < SIGD; m++) frow[m] = S[m];
    } else {
        const int ci  = i - 128;
        const int lt  = ci >> 1;
        const int chh = ci & 1;
        const int t   = quarter*64 + lt;
        const int loc = loc_base + lt;
        float xm[3], x0[3], xp[3];
        #pragma unroll
        for (int c = 0; c < 3; c++) {
            const float* xr = x + ((size_t)(b*3+c)*J_ + j)*T_;
            xm[c] = (t > 0)     ? xr[t-1] : 0.f;
            x0[c] = xr[t];
            xp[c] = (t < T_-1)  ? xr[t+1] : 0.f;
        }
        unsigned int packed[16];
        #pragma unroll
        for (int oo2 = 0; oo2 < 16; oo2++) {
            float r[2];
            #pragma unroll
            for (int e = 0; e < 2; e++) {
                int o = chh*32 + oo2*2 + e;
                float acc = conv_b[o];
                #pragma unroll
                for (int c = 0; c < 3; c++) {
                    const float* wr = conv_w + (o*3+c)*3;
                    acc += wr[0]*xm[c] + wr[1]*x0[c] + wr[2]*xp[c];
                }
                r[e] = fmaxf(acc, 0.f);
            }
            packed[oo2] = pack2(r[0], r[1]);
        }
        uint4* dst = (uint4*)(zcat + (size_t)loc*128 + chh*32);
        #pragma unroll
        for (int k = 0; k < 4; k++)
            dst[k] = make_uint4(packed[k*4+0], packed[k*4+1], packed[k*4+2], packed[k*4+3]);
    }
    __syncthreads();

    // ---- packed matvec: z_ps[loc][o] = relu(sum_k w[k][o]*f[loc][k]+cb) ----
    const int og = __builtin_amdgcn_readfirstlane(i >> 6);   // wave-uniform o-tile
    const int lt = i & 63;
    const int loc = loc_base + lt;
    const float* wt = wsig_t + og*16;        // + k*64
    f32x2 acc2[8];
    {
        const f32x2* cbp = (const f32x2*)(cb + og*16);
        #pragma unroll
        for (int p = 0; p < 8; p++) acc2[p] = cbp[p];
    }
    const float* frow = feats + lt*FSTR;
    #pragma unroll 8
    for (int k = 0; k < 2*SIGD; k++) {
        float f = frow[k];
        f32x2 f2 = { f, f };
        const f32x2* w2 = (const f32x2*)(wt + k*64);
        #pragma unroll
        for (int p = 0; p < 8; p++) acc2[p] += f2 * w2[p];   // v_pk_fma_f32
    }
    unsigned int pk[8];
    #pragma unroll
    for (int p = 0; p < 8; p++)
        pk[p] = pack2(fmaxf(acc2[p][0],0.f), fmaxf(acc2[p][1],0.f));
    uint4* dst = (uint4*)(zcat + (size_t)loc*128 + 64 + og*16);
    dst[0] = make_uint4(pk[0], pk[1], pk[2], pk[3]);
    dst[1] = make_uint4(pk[4], pk[5], pk[6], pk[7]);
}

// ---------------------------------------------------------------------------
// per-channel sum/ssq over [N_][128] bf16 (verified baseline r0).
// ---------------------------------------------------------------------------
template<int NCH>
__global__ __launch_bounds__(256) void k_stats(const unsigned short* __restrict__ z,
                                               float* __restrict__ sum,
                                               float* __restrict__ ssq) {
    constexpr int G  = NCH/8;
    constexpr int LP = 256/G;
    const int i = threadIdx.x;
    const int g = i % G;
    const int lr = i / G;
    const int base = blockIdx.x * 1600;
    float s[8], qq[8];
    #pragma unroll
    for (int k = 0; k < 8; k++) { s[k] = 0.f; qq[k] = 0.f; }
    for (int l = lr; l < 1600; l += LP) {
        const uint4 v = *(const uint4*)(z + (size_t)(base + l)*NCH + g*8);
        unsigned int u[4] = { v.x, v.y, v.z, v.w };
        #pragma unroll
        for (int k = 0; k < 4; k++) {
            float f0 = b2f(u[k] & 0xffffu);
            float f1 = __uint_as_float(u[k] & 0xffff0000u);
            s[2*k]   += f0;  qq[2*k]   += f0*f0;
            s[2*k+1] += f1;  qq[2*k+1] += f1*f1;
        }
    }
    const int lane = i & 63, wv = i >> 6;
    for (int off = 32; off >= G; off >>= 1) {
        #pragma unroll
        for (int k = 0; k < 8; k++) {
            s[k]  += __shfl_down(s[k],  off);
            qq[k] += __shfl_down(qq[k], off);
        }
    }
    __shared__ float red[4][G][16];
    if (lane < G) {
        #pragma unroll
        for (int k = 0; k < 8; k++) { red[wv][lane][k] = s[k]; red[wv][lane][8+k] = qq[k]; }
    }
    __syncthreads();
    if (i < G*16) {
        int g2 = i >> 4, slot = i & 15;
        float v = red[0][g2][slot] + red[1][g2][slot] + red[2][g2][slot] + red[3][g2][slot];
        int ch = g2*8 + (slot & 7);
        atomicAdd((slot < 8 ? sum : ssq) + ch, v);
    }
}

// ---------------------------------------------------------------------------
// K3: finalize conv/ps BN; fold into fu weights. (verified baseline r0)
// ---------------------------------------------------------------------------
__global__ void k_fin1(const float* __restrict__ sum_cp, const float* __restrict__ ssq_cp,
                       const float* __restrict__ raw_g, const float* __restrict__ raw_b,
                       const float* __restrict__ ps_g,  const float* __restrict__ ps_bt,
                       const float* __restrict__ fu_w,  const float* __restrict__ fu_b,
                       unsigned short* __restrict__ w12h, unsigned short* __restrict__ w12l,
                       float* __restrict__ w12s_t, float* __restrict__ fb2) {
    __shared__ float a[128], d[128];
    int i = threadIdx.x;    // 64
    const float inv = 1.f / (float)N_;
    {
        float m = sum_cp[i]*inv, v = ssq_cp[i]*inv - m*m;
        float sc = rsqrtf(v + 1e-5f) * raw_g[i];
        a[i] = sc; d[i] = raw_b[i] - m*sc;
    }
    {
        float m = sum_cp[64+i]*inv, v = ssq_cp[64+i]*inv - m*m;
        float sc = rsqrtf(v + 1e-5f) * ps_g[i];
        a[64+i] = sc; d[64+i] = ps_bt[i] - m*sc;
    }
    __syncthreads();
    int o = i;
    float fb = fu_b[o];
    for (int k = 0; k < 128; k++) {
        float w = fu_w[o*128 + k];
        fb += w * d[k];
        float ws = w * a[k];
        w12s_t[k*64 + o] = ws;
        unsigned short h, l;
        split2(ws, h, l);
        w12h[o*WST + k] = h;
        w12l[o*WST + k] = l;
    }
    for (int k = 128; k < WST; k++) { w12h[o*WST + k] = 0; w12l[o*WST + k] = 0; }
    fb2[o] = fb;
}

// ---------------------------------------------------------------------------
// K4: fu GEMM via MFMA with in-kernel C/D-orientation probe.
// NEW vs r9: okC path emits z_fu stats from REGISTERS (epilogue values,
// mrow-butterfly, 128 atomics/block — same count as r9) instead of the
// 50MB z_fu HBM read-back.  okT / scalar-fallback keep the r9 read-back
// post-pass (guarded, block-uniform) as the correctness net.
// ---------------------------------------------------------------------------
__global__ __launch_bounds__(256) void k_fu(const unsigned short* __restrict__ zcat,
                                            const unsigned short* __restrict__ w12h,
                                            const unsigned short* __restrict__ w12l,
                                            const float* __restrict__ w12s_t,
                                            const float* __restrict__ fb2,
                                            unsigned short* __restrict__ z_fu,
                                            float* __restrict__ sum_f,
                                            float* __restrict__ ssq_f) {
    __shared__ __align__(16) unsigned short zt[128*WST];   // 34816 B
    const int i = threadIdx.x;
    const int loc_base = blockIdx.x * 128;

    for (int c = i; c < 2048; c += 256) {
        int row = c >> 4, k = c & 15;
        s16x8 v = *(const s16x8*)(zcat + (size_t)(loc_base + row)*128 + k*8);
        *(s16x8*)(zt + row*WST + k*8) = v;
    }
    __syncthreads();

    const int lane = i & 63, wv = i >> 6;
    const int mrow = lane & 15, q = lane >> 4;
    const f32x4 zero = {0.f, 0.f, 0.f, 0.f};

    // ---- layout probe ----
    bf16x8 ap, bp;
    #pragma unroll
    for (int jj = 0; jj < 8; jj++) { ap[jj] = (__bf16)(float)mrow; bp[jj] = (__bf16)1.0f; }
    f32x4 pv = __builtin_amdgcn_mfma_f32_16x16x32_bf16(ap, bp, zero, 0, 0, 0);
    bool cC = true, cT = true;
    #pragma unroll
    for (int r = 0; r < 4; r++) {
        cC = cC && (pv[r] == 32.f*(float)(q*4 + r));
        cT = cT && (pv[r] == 32.f*(float)mrow);
    }
    const bool okC = (__ballot(cC) == ~0ull);
    const bool okT = (!okC) && (__ballot(cT) == ~0ull);

    if (okC || okT) {
        bf16x8 ah[4], al[4];
        {
            const unsigned short* arh = w12h + (size_t)(wv*16 + mrow)*WST + q*8;
            const unsigned short* arl = w12l + (size_t)(wv*16 + mrow)*WST + q*8;
            #pragma unroll
            for (int s = 0; s < 4; s++) {
                ah[s] = __builtin_bit_cast(bf16x8, *(const s16x8*)(arh + s*32));
                al[s] = __builtin_bit_cast(bf16x8, *(const s16x8*)(arl + s*32));
            }
        }
        f32x4 accs[8];
        #pragma unroll
        for (int lt8 = 0; lt8 < 8; lt8++) {
            const unsigned short* brow = zt + (size_t)(lt8*16 + mrow)*WST + q*8;
            f32x4 acc = zero;
            #pragma unroll
            for (int s = 0; s < 4; s++) {
                bf16x8 bfrag = __builtin_bit_cast(bf16x8, *(const s16x8*)(brow + s*32));
                acc = __builtin_amdgcn_mfma_f32_16x16x32_bf16(ah[s], bfrag, acc, 0, 0, 0);
                acc = __builtin_amdgcn_mfma_f32_16x16x32_bf16(al[s], bfrag, acc, 0, 0, 0);
            }
            accs[lt8] = acc;
        }
        __syncthreads();

        unsigned short* ot = zt;       // alias as [128 loc][72 o]
        if (okC) {
            const float4 fbv = *(const float4*)(fb2 + wv*16 + q*4);
            float ls[4], lq[4];
            #pragma unroll
            for (int r = 0; r < 4; r++) { ls[r] = 0.f; lq[r] = 0.f; }
            #pragma unroll
            for (int lt8 = 0; lt8 < 8; lt8++) {
                int row = lt8*16 + mrow;
                int o   = wv*16 + q*4;
                float r0 = fmaxf(accs[lt8][0]+fbv.x, 0.f);
                float r1 = fmaxf(accs[lt8][1]+fbv.y, 0.f);
                float r2 = fmaxf(accs[lt8][2]+fbv.z, 0.f);
                float r3 = fmaxf(accs[lt8][3]+fbv.w, 0.f);
                ls[0] += r0; lq[0] += r0*r0;
                ls[1] += r1; lq[1] += r1*r1;
                ls[2] += r2; lq[2] += r2*r2;
                ls[3] += r3; lq[3] += r3*r3;
                uint2 w;
                w.x = pack2(r0, r1);
                w.y = pack2(r2, r3);
                *(uint2*)(ot + row*72 + o) = w;
            }
            // reduce over the 16 mrow-lanes of this q-group (whole wave active)
            #pragma unroll
            for (int off = 1; off <= 8; off <<= 1) {
                #pragma unroll
                for (int r = 0; r < 4; r++) {
                    ls[r] += __shfl_xor(ls[r], off);
                    lq[r] += __shfl_xor(lq[r], off);
                }
            }
            if (mrow == 0) {
                const int ob   = wv*16 + q*4;
                const int slot = blockIdx.x & (NSLOT-1);
                #pragma unroll
                for (int r = 0; r < 4; r++) {
                    atomicAdd(sum_f + slot*64 + ob + r, ls[r]);
                    atomicAdd(ssq_f + slot*64 + ob + r, lq[r]);
                }
            }
        } else {
            const float fb1 = fb2[wv*16 + mrow];
            #pragma unroll
            for (int lt8 = 0; lt8 < 8; lt8++) {
                #pragma unroll
                for (int r = 0; r < 4; r++) {
                    int row = lt8*16 + q*4 + r;
                    ot[row*72 + wv*16 + mrow] = f2b(fmaxf(accs[lt8][r]+fb1, 0.f));
                }
            }
        }
        __syncthreads();
        for (int c = i; c < 1024; c += 256) {
            int row = c >> 3, k = c & 7;
            s16x8 v = *(const s16x8*)(ot + row*72 + k*8);
            *(s16x8*)(z_fu + (size_t)(loc_base + row)*64 + k*8) = v;
        }
    } else {
        // ---- scalar fallback (correctness net; slow but exact) ----
        if (i < 128) {
            const unsigned short* fr = zt + i*WST;
            const int loc = loc_base + i;
            for (int og8 = 0; og8 < 8; og8++) {
                float acc[8];
                #pragma unroll
                for (int p = 0; p < 8; p++) acc[p] = fb2[og8*8 + p];
                for (int k = 0; k < 128; k++) {
                    float f = b2f(fr[k]);
                    const float* w = w12s_t + k*64 + og8*8;
                    #pragma unroll
                    for (int p = 0; p < 8; p++) acc[p] = fmaf(f, w[p], acc[p]);
                }
                #pragma unroll
                for (int p = 0; p < 8; p++)
                    z_fu[(size_t)loc*64 + og8*8 + p] = f2b(fmaxf(acc[p], 0.f));
            }
        }
    }

    // ---- stats read-back net: ONLY for non-okC paths (okT / fallback) ----
    if (!okC) {
        __syncthreads();    // z_fu stores drained; zt reads finished -> reuse
        const int g3  = i & 7;           // 8 channel-groups of 8
        const int lr3 = i >> 3;
        float s[8], q2[8];
        #pragma unroll
        for (int k = 0; k < 8; k++) { s[k] = 0.f; q2[k] = 0.f; }
        #pragma unroll
        for (int li = 0; li < 4; li++) {
            const int l = lr3 + li*32;
            const uint4 v = *(const uint4*)(z_fu + (size_t)(loc_base + l)*64 + g3*8);
            unsigned int u[4] = { v.x, v.y, v.z, v.w };
            #pragma unroll
            for (int k = 0; k < 4; k++) {
                float f0 = b2f(u[k] & 0xffffu);
                float f1 = __uint_as_float(u[k] & 0xffff0000u);
                s[2*k]   += f0;  q2[2*k]   += f0*f0;
                s[2*k+1] += f1;  q2[2*k+1] += f1*f1;
            }
        }
        #pragma unroll
        for (int off = 8; off <= 32; off <<= 1) {
            #pragma unroll
            for (int k = 0; k < 8; k++) {
                s[k]  += __shfl_xor(s[k],  off);
                q2[k] += __shfl_xor(q2[k], off);
            }
        }
        float* red = (float*)zt;         // [4 wv][8 g][16] = 512 floats
        if (lane < 8) {                  // lane == g3 here
            #pragma unroll
            for (int k = 0; k < 8; k++) {
                red[(wv*8 + g3)*16 + k]     = s[k];
                red[(wv*8 + g3)*16 + 8 + k] = q2[k];
            }
        }
        __syncthreads();
        if (i < 128) {
            const int ch = i >> 1, which = i & 1;
            const int g = ch >> 3, k = ch & 7;
            const int idx = which*8 + k;
            float t0 = red[(0*8+g)*16 + idx] + red[(1*8+g)*16 + idx]
                     + red[(2*8+g)*16 + idx] + red[(3*8+g)*16 + idx];
            const int slot = blockIdx.x & (NSLOT-1);
            atomicAdd((which ? ssq_f : sum_f) + slot*64 + ch, t0);
        }
    }
}

// ---------------------------------------------------------------------------
// K5: finalize fu BN stats (NSLOT-slot sums) — verified r7/r8/r9
// ---------------------------------------------------------------------------
__global__ void k_fin2(const float* __restrict__ sum_f, const float* __restrict__ ssq_f,
                       const float* __restrict__ fu_g,
                       float* __restrict__ mf, float* __restrict__ rfg) {
    int o = threadIdx.x;
    const float inv = 1.f / (float)N_;
    float sm = 0.f, sq = 0.f;
    for (int sl = 0; sl < NSLOT; sl++) { sm += sum_f[sl*64 + o]; sq += ssq_f[sl*64 + o]; }
    float m = sm*inv, v = sq*inv - m*m;
    mf[o] = m;
    rfg[o] = rsqrtf(v + 1e-5f) * fu_g[o];
}

// ---------------------------------------------------------------------------
// K6: apply fu BN, transpose [loc][64] -> out [b][o][j][t] f32. (verified r0)
// ---------------------------------------------------------------------------
__global__ __launch_bounds__(256) void k_out(const unsigned short* __restrict__ z_fu,
                                             const float* __restrict__ mf,
                                             const float* __restrict__ rfg,
                                             const float* __restrict__ fu_beta,
                                             float* __restrict__ out) {
    __shared__ __align__(16) unsigned short zt[256*66];
    const int i = threadIdx.x;
    const int bj = blockIdx.x;
    const int b = bj / J_, j = bj % J_;
    const int loc_base = bj * T_;

    for (int c = i; c < 2048; c += 256) {
        int row = c >> 3, k = c & 7;
        uint4 v = *(const uint4*)(z_fu + (size_t)(loc_base + row)*64 + k*8);
        unsigned int* dst = (unsigned int*)(zt + row*66 + k*8);
        dst[0] = v.x; dst[1] = v.y; dst[2] = v.z; dst[3] = v.w;
    }
    __syncthreads();

    const int t = i;
    const unsigned int* zrow = (const unsigned int*)zt + t*33;
    for (int o = 0; o < 64; o += 2) {
        unsigned int v = zrow[o >> 1];
        float f0 = b2f(v & 0xffffu);
        float f1 = __uint_as_float(v & 0xffff0000u);
        out[(((size_t)b*64 + o  )*J_ + j)*T_ + t] = (f0 - mf[o  ])*rfg[o  ] + fu_beta[o  ];
        out[(((size_t)b*64 + o+1)*J_ + j)*T_ + t] = (f1 - mf[o+1])*rfg[o+1] + fu_beta[o+1];
    }
}

// ---------------------------------------------------------------------------
extern "C" void kernel_launch(void* const* d_in, const int* in_sizes, int n_in,
                              void* d_out, int out_size, void* d_ws, size_t ws_size,
                              hipStream_t stream) {
    const float* x         = (const float*)d_in[0];
    const float* conv_w    = (const float*)d_in[1];
    const float* conv_b    = (const float*)d_in[2];
    const float* raw_gamma = (const float*)d_in[3];
    const float* raw_beta  = (const float*)d_in[4];
    const float* sp_W      = (const float*)d_in[5];
    const float* sp_b      = (const float*)d_in[6];
    const float* tp_W      = (const float*)d_in[7];
    const float* tp_b      = (const float*)d_in[8];
    const float* ps_w      = (const float*)d_in[9];
    const float* ps_b      = (const float*)d_in[10];
    const float* ps_gamma  = (const float*)d_in[11];
    const float* ps_beta   = (const float*)d_in[12];
    const float* fu_w      = (const float*)d_in[13];
    const float* fu_b      = (const float*)d_in[14];
    const float* fu_gamma  = (const float*)d_in[15];
    const float* fu_beta   = (const float*)d_in[16];
    const int*   neighbors = (const int*)d_in[17];

    char* ws = (char*)d_ws;
    unsigned short* zcat   = (unsigned short*)ws;                      // [N][128] bf16
    unsigned short* z_fu   = (unsigned short*)(ws + 104857600);        // [N][64] bf16
    size_t off = 157286400;
    float* wsig_t = (float*)(ws + off);          off += 168*64*4;      // [168][64] f32
    float* w12s_t = (float*)(ws + off);          off += 128*64*4;      // [128][64] f32
    unsigned short* w12h = (unsigned short*)(ws + off); off += 64*WST*2;
    unsigned short* w12l = (unsigned short*)(ws + off); off += 64*WST*2;
    float* f32s   = (float*)(ws + off);
    float* cb     = f32s;                         // 64
    float* fb2    = f32s + 64;                    // 64
    float* mf     = f32s + 128;                   // 64
    float* rfg    = f32s + 192;                   // 64
    float* sum_cp = f32s + 256;                   // 128
    float* ssq_cp = f32s + 384;                   // 128
    float* sum_f  = f32s + 512;                   // NSLOT*64
    float* ssq_f  = sum_f + NSLOT*64;             // NSLOT*64

    hipMemsetAsync(sum_cp, 0, (size_t)(256 + NSLOT*128)*sizeof(float), stream);

    k_prep<<<169, 64, 0, stream>>>(sp_W, sp_b, tp_W, tp_b, ps_w, ps_b, wsig_t, cb);
    k_sig<<<6400, 256, 0, stream>>>(x, neighbors, wsig_t, cb, conv_w, conv_b, zcat);
    k_stats<128><<<256, 256, 0, stream>>>(zcat, sum_cp, ssq_cp);
    k_fin1<<<1, 64, 0, stream>>>(sum_cp, ssq_cp, raw_gamma, raw_beta,
                                 ps_gamma, ps_beta, fu_w, fu_b,
                                 w12h, w12l, w12s_t, fb2);
    k_fu<<<3200, 256, 0, stream>>>(zcat, w12h, w12l, w12s_t, fb2, z_fu,
                                   sum_f, ssq_f);
    k_fin2<<<1, 64, 0, stream>>>(sum_f, ssq_f, fu_gamma, mf, rfg);
    k_out<<<1600, 256, 0, stream>>>(z_fu, mf, rfg, fu_beta, (float*)d_out);
}